// Round 6
// baseline (1046.085 us; speedup 1.0000x reference)
//
#include <hip/hip_runtime.h>
#include <hip/hip_bf16.h>
#include <stdint.h>

// GATv2Conv(1028->256, heads=1, self-loops) on gfx950, fp32 in/out.
// Pipeline: prep(W^T->bf16, degree hist) -> fused fp32->bf16 MFMA GEMM
// (reads x fp32 directly, converts in A-staging; xl|xr -> bf16 xf) -> scan
// -> scatter (CSR) -> fused per-dst online-softmax gather.
// R6: grid-stride/MLP/transpose-tile changes left k_prep at ~153us @1.75TB/s
// (invariant to structure) -> the x->bf16 pass itself is the cost. R8: delete
// it. GEMM A-staging now loads x fp32 (2x dwordx4/lane), converts via
// v_cvt_pk_bf16_f32, ds_write_b128 into the same LDS layout. Grid swapped to
// dim3(4, 391) so the 4 N-siblings of an M-panel are dispatch-consecutive
// (share the A-panel via L3; avoids 4x re-fetch of 205MB x).
// R9/R10/R11: identical resubmits — benches hit GPUAcquisitionTimeout.

#define N_NODES 50000
#define N_EDGES 1600000
#define D_IN    1028
#define KPAD    1056   // K padded to x32; A-pad zeroed at staging, Wt zero-filled
#define D_OUT   256
#define NB      512    // xf row: cols [0,256)=xl, [256,512)=xr

// k_prep segments
#define WT_TILES   (33 * 8)                 // 32k x 64n tiles: 1056/32=33, 512/64=8
#define HIST_GS    1024                     // grid-stride blocks for degree hist
#define PREP_BLOCKS (WT_TILES + HIST_GS)
#define SCAT_GS    2048

typedef __bf16 bf16x8 __attribute__((ext_vector_type(8)));
typedef float  f32x4  __attribute__((ext_vector_type(4)));

static __device__ __forceinline__ void gl_lds16(const void* g, void* l) {
  __builtin_amdgcn_global_load_lds(
      (const __attribute__((address_space(1))) unsigned int*)g,
      (__attribute__((address_space(3))) unsigned int*)l, 16, 0, 0);
}
static __device__ __forceinline__ unsigned short f2bf(float f) {
  union { float f; unsigned int i; } c; c.f = f;
  unsigned int r = 0x7fffu + ((c.i >> 16) & 1u);  // round-to-nearest-even
  return (unsigned short)((c.i + r) >> 16);
}
// packed 2xf32 -> 2xbf16 (RNE), gfx950 hw op (no builtin; asm per learn_hip m214)
static __device__ __forceinline__ unsigned int cvt_pk_bf16(float lo, float hi) {
  unsigned int r;
  asm("v_cvt_pk_bf16_f32 %0, %1, %2" : "=v"(r) : "v"(lo), "v"(hi));
  return r;
}

// ---------------- edge_index dtype autodetect --------------------------------
// Values < 50000: if data is int64, high word of every entry is 0.
// mode==0 -> int64, mode!=0 -> int32.
__global__ void k_mode(const unsigned int* __restrict__ ei32, int* __restrict__ mode) {
  int t = blockIdx.x * 256 + threadIdx.x;  // 2048 probes
  if (t < 2048 && ei32[2 * t + 1] != 0u) atomicOr(mode, 1);
}

static __device__ __forceinline__ int load_idx(const int* ei, int md, int pos, int n) {
  int v = md ? ei[pos] : (int)((const long long*)ei)[pos];
  return v < 0 ? 0 : (v >= n ? n - 1 : v);
}

// ---------------- prep: W^T -> bf16 | degree hist ----------------------------
__global__ __launch_bounds__(256) void k_prep(const float* __restrict__ Wl,
    const float* __restrict__ Wr, const int* __restrict__ ei,
    const int* __restrict__ mode, unsigned short* __restrict__ Wt,
    int* __restrict__ deg) {
  __shared__ unsigned short tile[32][66];  // pad 66: read-phase bank = k mod 32
  const int b = blockIdx.x, t = threadIdx.x;
  if (b < WT_TILES) {
    // LDS-tiled transpose: 32k x 64n tile, both global sides coalesced.
    const int k0 = (b >> 3) * 32, n0 = (b & 7) * 64;
#pragma unroll
    for (int j = 0; j < 8; ++j) {          // load: consecutive t -> consecutive n
      int k = 4 * j + (t >> 6), n = t & 63;
      unsigned short val = 0;
      if (k0 + k < D_IN) {
        int gn = n0 + n;
        val = f2bf(gn < D_OUT ? Wl[(size_t)(k0 + k) * D_OUT + gn]
                              : Wr[(size_t)(k0 + k) * D_OUT + (gn - D_OUT)]);
      }
      tile[k][n] = val;
    }
    __syncthreads();
#pragma unroll
    for (int j = 0; j < 8; ++j) {          // store: consecutive t -> consecutive k
      int n = 8 * j + (t >> 5), k = t & 31;
      Wt[(size_t)(n0 + n) * KPAD + k0 + k] = tile[k][n];
    }
  } else {
    // degree histogram, grid-stride
    const int md = *mode;
    const int TH = HIST_GS * 256;
    for (int e = (b - WT_TILES) * 256 + t; e < N_EDGES; e += TH) {
      int d = load_idx(ei, md, N_EDGES + e, N_NODES);
      atomicAdd(&deg[d], 1);
    }
  }
}

// ---------------- GEMM: xf[M][512] = x[M][.](fp32) @ Wt^T (bf16 MFMA) -------
// 128x128 tile, BK=32, 16x16x32 mfma, 4 waves each 64x64.
// A: reg-staged fp32 load + cvt_pk_bf16 + ds_write (fused prep).
// B: global_load_lds from prepped bf16 Wt.
// Grid is dim3(4, 391): n-tile fastest so the 4 siblings sharing an A-panel
// are dispatch-consecutive (L3 serves 3 of 4).
__global__ __launch_bounds__(256) void k_gemm(const float* __restrict__ x,
                                              const unsigned short* __restrict__ Wt,
                                              unsigned short* __restrict__ xf, int M) {
  __shared__ unsigned short smem[16896];  // As[0,4096) Bs[4096,8192); Cs overlays (128x132)
  unsigned short* As = smem;
  unsigned short* Bs = smem + 4096;
  unsigned short* Cs = smem;
  const int tid = threadIdx.x;
  const int w = tid >> 6, lane = tid & 63;
  const int m0 = blockIdx.y * 128, n0 = blockIdx.x * 128;
  const int wm = (w >> 1) * 64, wn = (w & 1) * 64;

  f32x4 zero = {0.f, 0.f, 0.f, 0.f};
  f32x4 acc[4][4];
#pragma unroll
  for (int i = 0; i < 4; ++i)
#pragma unroll
    for (int j = 0; j < 4; ++j) acc[i][j] = zero;

  const int lrow = lane >> 2, lch = lane & 3;  // 16 rows x 4 chunks per group

  for (int k0 = 0; k0 < KPAD; k0 += 32) {
    __syncthreads();
    // A: fp32 -> bf16, reg-staged. Per group j: 16 rows, lane covers row
    // lrow, K-cols [lch*8, lch*8+8). Two float4 loads, 4 cvt_pk, 1 b128 write.
    float4 f[4];
    int gka = k0 + lch * 8;
#pragma unroll
    for (int j = 0; j < 2; ++j) {
      int gm = m0 + w * 32 + j * 16 + lrow;
      if (gm >= M) gm = M - 1;
      const float* gp = x + (size_t)gm * D_IN + gka;
      f[2 * j]     = (gka     < D_IN) ? *(const float4*)gp       : *(const float4*)&zero;
      f[2 * j + 1] = (gka + 4 < D_IN) ? *(const float4*)(gp + 4) : *(const float4*)&zero;
    }
    // B: async global->LDS from bf16 Wt (zero-padded at prep)
#pragma unroll
    for (int j = 0; j < 2; ++j) {
      int gn = n0 + w * 32 + j * 16 + lrow;
      const char* g = (const char*)Wt + ((size_t)gn * KPAD + k0) * 2 + lch * 16;
      gl_lds16(g, &Bs[(w * 32 + j * 16) * 32]);
    }
#pragma unroll
    for (int j = 0; j < 2; ++j) {
      uint4 pk;
      pk.x = cvt_pk_bf16(f[2 * j].x,     f[2 * j].y);
      pk.y = cvt_pk_bf16(f[2 * j].z,     f[2 * j].w);
      pk.z = cvt_pk_bf16(f[2 * j + 1].x, f[2 * j + 1].y);
      pk.w = cvt_pk_bf16(f[2 * j + 1].z, f[2 * j + 1].w);
      *(uint4*)&As[(w * 32 + j * 16 + lrow) * 32 + lch * 8] = pk;
    }
    __syncthreads();

    bf16x8 af[4], bfr[4];
#pragma unroll
    for (int t = 0; t < 4; ++t)
      af[t] = *(const bf16x8*)&As[(wm + t * 16 + (lane & 15)) * 32 + (lane >> 4) * 8];
#pragma unroll
    for (int t = 0; t < 4; ++t)
      bfr[t] = *(const bf16x8*)&Bs[(wn + t * 16 + (lane & 15)) * 32 + (lane >> 4) * 8];
#pragma unroll
    for (int mt = 0; mt < 4; ++mt)
#pragma unroll
      for (int nt = 0; nt < 4; ++nt)
        acc[mt][nt] = __builtin_amdgcn_mfma_f32_16x16x32_bf16(af[mt], bfr[nt], acc[mt][nt], 0, 0, 0);
  }

  // C/D layout: col = lane&15, row = (lane>>4)*4 + r
  __syncthreads();  // all As/Bs reads done before Cs overlay
  {
    const int col = lane & 15, rq = (lane >> 4) * 4;
#pragma unroll
    for (int mt = 0; mt < 4; ++mt)
#pragma unroll
      for (int nt = 0; nt < 4; ++nt)
#pragma unroll
        for (int r = 0; r < 4; ++r)
          Cs[(wm + mt * 16 + rq + r) * 132 + wn + nt * 16 + col] = f2bf(acc[mt][nt][r]);
  }
  __syncthreads();
  {
    const int row = tid >> 1, half = tid & 1;  // 2 threads per row, 128B each
    int gm = m0 + row;
    if (gm < M) {
      unsigned short* dst = xf + (size_t)gm * NB + n0 + half * 64;
      const unsigned short* srcp = &Cs[row * 132 + half * 64];
#pragma unroll
      for (int j = 0; j < 8; ++j)
        *(uint4*)(dst + j * 8) = *(const uint4*)(srcp + j * 8);
    }
  }
}

// ---------------- 3-phase single-block exclusive scan (n=50000) --------------
__global__ __launch_bounds__(1024) void k_scan(const int* __restrict__ deg,
    int* __restrict__ rowstart, int* __restrict__ cursor, int n) {
  const int t = (int)threadIdx.x;
  const int lane = t & 63, wid = t >> 6;
  const int seg = (n + 1023) / 1024;   // 49
  const int base = t * seg;
  __shared__ int wsum[16];

  int sum = 0;
  for (int j = 0; j < seg; ++j) { int i = base + j; if (i < n) sum += deg[i]; }

  int x = sum;                                    // wave inclusive scan
#pragma unroll
  for (int off = 1; off < 64; off <<= 1) {
    int y = __shfl_up(x, off, 64);
    if (lane >= off) x += y;
  }
  if (lane == 63) wsum[wid] = x;
  __syncthreads();
  if (t < 16) {                                   // exclusive scan of 16 wave sums
    int v = wsum[t], s = v;
#pragma unroll
    for (int off = 1; off < 16; off <<= 1) {
      int y = __shfl_up(s, off, 16);
      if (t >= off) s += y;
    }
    wsum[t] = s - v;
  }
  __syncthreads();
  int run = wsum[wid] + (x - sum);                // exclusive prefix for thread t
  for (int j = 0; j < seg; ++j) {
    int i = base + j;
    if (i < n) { rowstart[i] = run; cursor[i] = run; run += deg[i]; }
  }
  if (t == 1023) rowstart[n] = run;
}

__global__ __launch_bounds__(256) void k_scatter(const int* __restrict__ ei,
                          const int* __restrict__ mode,
                          int* __restrict__ cursor, int* __restrict__ ssrc) {
  const int md = *mode;
  const int TH = SCAT_GS * 256;
  for (int e = (int)blockIdx.x * 256 + (int)threadIdx.x; e < N_EDGES; e += TH) {
    int s = load_idx(ei, md, e, N_NODES);
    int d = load_idx(ei, md, N_EDGES + e, N_NODES);
    int pos = atomicAdd(&cursor[d], 1);
    if (pos >= 0 && pos < N_EDGES) ssrc[pos] = s;
  }
}

// ---------------- fused gather + online softmax + aggregate ------------------
// Wave = 2 groups x 32 lanes; lane covers dims [8*gl, 8*gl+8). Each group
// processes alternating edges of the same dst; flash-merge at the end.
static __device__ __forceinline__ void unpack8(uint4 u, float* v) {
  union { unsigned int i; float f; } c;
  c.i = u.x << 16;         v[0] = c.f;
  c.i = u.x & 0xffff0000u; v[1] = c.f;
  c.i = u.y << 16;         v[2] = c.f;
  c.i = u.y & 0xffff0000u; v[3] = c.f;
  c.i = u.z << 16;         v[4] = c.f;
  c.i = u.z & 0xffff0000u; v[5] = c.f;
  c.i = u.w << 16;         v[6] = c.f;
  c.i = u.w & 0xffff0000u; v[7] = c.f;
}
static __device__ __forceinline__ float dot8(const float* v, const float* xr, const float* a) {
  float e = 0.f;
#pragma unroll
  for (int d = 0; d < 8; ++d) {
    float t = v[d] + xr[d];
    t = fmaxf(t, 0.2f * t);        // LeakyReLU(0.2): max(t, 0.2t)
    e = fmaf(a[d], t, e);
  }
  return e;
}
static __device__ __forceinline__ float red32(float e) {
#pragma unroll
  for (int off = 1; off < 32; off <<= 1) e += __shfl_xor(e, off, 64);
  return e;
}

__global__ __launch_bounds__(256) void k_gat(const unsigned short* __restrict__ xf,
    const int* __restrict__ rowstart, const int* __restrict__ ssrc,
    const float* __restrict__ att, const float* __restrict__ bias,
    float* __restrict__ out, int n) {
  const int gw = (int)blockIdx.x * 4 + (int)(threadIdx.x >> 6);  // 1 wave/dst
  const int lane = (int)(threadIdx.x & 63);
  const int grp = lane >> 5, gl = lane & 31;
  if (gw >= n) return;

  float a[8];
  {
    float4 A0 = ((const float4*)att)[2 * gl];
    float4 A1 = ((const float4*)att)[2 * gl + 1];
    a[0] = A0.x; a[1] = A0.y; a[2] = A0.z; a[3] = A0.w;
    a[4] = A1.x; a[5] = A1.y; a[6] = A1.z; a[7] = A1.w;
  }
  float xr[8], vs[8];
  unpack8(*(const uint4*)(xf + (size_t)gw * NB + D_OUT + 8 * gl), xr);
  unpack8(*(const uint4*)(xf + (size_t)gw * NB + 8 * gl), vs);   // self row (xl)

  // self-loop into group 0; group 1 starts empty
  float m, l, acc[8];
  {
    float e = red32(dot8(vs, xr, a));
    if (grp == 0) {
      m = e; l = 1.f;
#pragma unroll
      for (int d = 0; d < 8; ++d) acc[d] = vs[d];
    } else {
      m = -1e30f; l = 0.f;
#pragma unroll
      for (int d = 0; d < 8; ++d) acc[d] = 0.f;
    }
  }

  const int end = rowstart[gw + 1];
  int i = rowstart[gw] + grp;                     // group g: edges beg+g, +2, ...
  bool have = i < end;
  uint4 vu;
  if (have) {
    unsigned s = (unsigned)ssrc[i];
    vu = *(const uint4*)(xf + ((size_t)s << 9) + 8 * gl);
  }
  while (have) {
    int i2 = i + 2;
    bool have2 = i2 < end;
    uint4 vu2;
    if (have2) {                                  // depth-2 pipeline: prefetch
      unsigned s2 = (unsigned)ssrc[i2];
      vu2 = *(const uint4*)(xf + ((size_t)s2 << 9) + 8 * gl);
    }
    float v[8];
    unpack8(vu, v);
    float e = red32(dot8(v, xr, a));
    float mn = fmaxf(m, e);
    float sc = __expf(m - mn);
    float p  = __expf(e - mn);
#pragma unroll
    for (int d = 0; d < 8; ++d) acc[d] = fmaf(p, v[d], acc[d] * sc);
    l = fmaf(l, sc, p);
    m = mn;
    vu = vu2; i = i2; have = have2;
  }

  // flash-merge the two groups (lane L and L+32 hold the same dims)
  float mo = __shfl_xor(m, 32, 64);
  float mM = fmaxf(m, mo);
  float sA = __expf(m - mM);
  float lA = l * sA;
  float lS = lA + __shfl_xor(lA, 32, 64);
  float inv = 1.f / lS;
#pragma unroll
  for (int d = 0; d < 8; ++d) {
    float t = acc[d] * sA;
    acc[d] = t + __shfl_xor(t, 32, 64);
  }
  if (grp == 0) {
    float4 B0 = ((const float4*)bias)[2 * gl];
    float4 B1 = ((const float4*)bias)[2 * gl + 1];
    float4 o0, o1;
    o0.x = fmaf(acc[0], inv, B0.x); o0.y = fmaf(acc[1], inv, B0.y);
    o0.z = fmaf(acc[2], inv, B0.z); o0.w = fmaf(acc[3], inv, B0.w);
    o1.x = fmaf(acc[4], inv, B1.x); o1.y = fmaf(acc[5], inv, B1.y);
    o1.z = fmaf(acc[6], inv, B1.z); o1.w = fmaf(acc[7], inv, B1.w);
    ((float4*)out)[(size_t)gw * 64 + 2 * gl] = o0;
    ((float4*)out)[(size_t)gw * 64 + 2 * gl + 1] = o1;
  }
}

// ---------------- launch -----------------------------------------------------
extern "C" void kernel_launch(void* const* d_in, const int* in_sizes, int n_in,
                              void* d_out, int out_size, void* d_ws, size_t ws_size,
                              hipStream_t stream) {
  (void)in_sizes; (void)n_in; (void)out_size; (void)ws_size;
  const float* x   = (const float*)d_in[0];
  const int*   ei  = (const int*)d_in[1];
  const float* Wl  = (const float*)d_in[2];
  const float* Wr  = (const float*)d_in[3];
  const float* att = (const float*)d_in[4];
  const float* bia = (const float*)d_in[5];
  float* out = (float*)d_out;

  const int N = N_NODES;
  const int E = N_EDGES;

  char* ws = (char*)d_ws;
  size_t off = 0;
  unsigned short* xf = (unsigned short*)(ws + off); off += (size_t)N * NB * 2;    //  51.2 MB
  unsigned short* Wt = (unsigned short*)(ws + off); off += (size_t)NB * KPAD * 2; //   1.1 MB
  off = (off + 255) & ~(size_t)255;
  int* deg      = (int*)(ws + off); off += (size_t)N * 4;
  int* mode     = (int*)(ws + off); off += 256;   // adjacent to deg: one memset
  int* rowstart = (int*)(ws + off); off += (size_t)(N + 1) * 4;
  off = (off + 255) & ~(size_t)255;
  int* cursor   = (int*)(ws + off); off += (size_t)N * 4;
  int* ssrc     = (int*)(ws + off); off += (size_t)E * 4;   // total ~60 MB

  hipMemsetAsync(deg, 0, (size_t)N * 4 + 256, stream);      // deg + mode
  k_mode<<<8, 256, 0, stream>>>((const unsigned int*)ei, mode);
  k_prep<<<PREP_BLOCKS, 256, 0, stream>>>(Wl, Wr, ei, mode, Wt, deg);
  k_gemm<<<dim3(NB / 128, (N + 127) / 128), 256, 0, stream>>>(x, Wt, xf, N);
  k_scan<<<1, 1024, 0, stream>>>(deg, rowstart, cursor, N);
  k_scatter<<<SCAT_GS, 256, 0, stream>>>(ei, mode, cursor, ssrc);
  k_gat<<<(N + 3) / 4, 256, 0, stream>>>(xf, rowstart, ssrc, att, bia, out, N);
}

// Round 7
// 1036.629 us; speedup vs baseline: 1.0091x; 1.0091x over previous
//
#include <hip/hip_runtime.h>
#include <hip/hip_bf16.h>
#include <stdint.h>

// GATv2Conv(1028->256, heads=1, self-loops) on gfx950, fp32 in/out.
// Pipeline: prep(W^T->bf16, degree hist) -> fused fp32->bf16 MFMA GEMM
// (reads x fp32 directly, converts in A-staging) -> scan -> scatter (CSR)
// -> fused per-dst online-softmax gather.
// R8 result: k_gemm 374us, MfmaUtil 5.8%, 1.48TB/s, FETCH 491MB, occ 27%
// -> sync A-staging serialized load->use every K-step; dim3(4,391) siblings
// landed on different XCDs (round-robin) and race-fetched the A-panel.
// R12: (a) prefetch next K-step's x loads right after the tile-ready barrier
// (fly under MFMA phase); (b) XCD-grouped 1D grid: id%8==m%8 puts all 4
// N-siblings on ONE XCD -> A-panel fetched once into that L2; (c) XOR chunk
// swizzle on As write + pre-swizzled GLOBAL source for Bs (gl_lds dest must
// stay linear, m104/m173) -> frag-read conflicts 8->4 way; (d) epilogue in
// two 64-col passes (stride 72, 16B-aligned) -> LDS 33.8->18KB.

#define N_NODES 50000
#define N_EDGES 1600000
#define D_IN    1028
#define KPAD    1056   // K padded to x32; A-pad zeroed at staging, Wt zero-filled
#define D_OUT   256
#define NB      512    // xf row: cols [0,256)=xl, [256,512)=xr

#define M_TILES 391    // ceil(50000/128)
#define NXCD    8
#define MQ      ((M_TILES + NXCD - 1) / NXCD)       // 49
#define GEMM_BLOCKS (NXCD * MQ * 4)                 // 1568 (4 idle)

// k_prep segments
#define WT_TILES   (33 * 8)                 // 32k x 64n tiles: 1056/32=33, 512/64=8
#define HIST_GS    1024                     // grid-stride blocks for degree hist
#define PREP_BLOCKS (WT_TILES + HIST_GS)
#define SCAT_GS    2048

typedef __bf16 bf16x8 __attribute__((ext_vector_type(8)));
typedef float  f32x4  __attribute__((ext_vector_type(4)));

static __device__ __forceinline__ void gl_lds16(const void* g, void* l) {
  __builtin_amdgcn_global_load_lds(
      (const __attribute__((address_space(1))) unsigned int*)g,
      (__attribute__((address_space(3))) unsigned int*)l, 16, 0, 0);
}
static __device__ __forceinline__ unsigned short f2bf(float f) {
  union { float f; unsigned int i; } c; c.f = f;
  unsigned int r = 0x7fffu + ((c.i >> 16) & 1u);  // round-to-nearest-even
  return (unsigned short)((c.i + r) >> 16);
}
// packed 2xf32 -> 2xbf16 (RNE), gfx950 hw op (no builtin; asm per learn_hip m214)
static __device__ __forceinline__ unsigned int cvt_pk_bf16(float lo, float hi) {
  unsigned int r;
  asm("v_cvt_pk_bf16_f32 %0, %1, %2" : "=v"(r) : "v"(lo), "v"(hi));
  return r;
}

// ---------------- edge_index dtype autodetect --------------------------------
__global__ void k_mode(const unsigned int* __restrict__ ei32, int* __restrict__ mode) {
  int t = blockIdx.x * 256 + threadIdx.x;  // 2048 probes
  if (t < 2048 && ei32[2 * t + 1] != 0u) atomicOr(mode, 1);
}

static __device__ __forceinline__ int load_idx(const int* ei, int md, int pos, int n) {
  int v = md ? ei[pos] : (int)((const long long*)ei)[pos];
  return v < 0 ? 0 : (v >= n ? n - 1 : v);
}

// ---------------- prep: W^T -> bf16 | degree hist ----------------------------
__global__ __launch_bounds__(256) void k_prep(const float* __restrict__ Wl,
    const float* __restrict__ Wr, const int* __restrict__ ei,
    const int* __restrict__ mode, unsigned short* __restrict__ Wt,
    int* __restrict__ deg) {
  __shared__ unsigned short tile[32][66];  // pad 66: read-phase bank = k mod 32
  const int b = blockIdx.x, t = threadIdx.x;
  if (b < WT_TILES) {
    // LDS-tiled transpose: 32k x 64n tile, both global sides coalesced.
    const int k0 = (b >> 3) * 32, n0 = (b & 7) * 64;
#pragma unroll
    for (int j = 0; j < 8; ++j) {          // load: consecutive t -> consecutive n
      int k = 4 * j + (t >> 6), n = t & 63;
      unsigned short val = 0;
      if (k0 + k < D_IN) {
        int gn = n0 + n;
        val = f2bf(gn < D_OUT ? Wl[(size_t)(k0 + k) * D_OUT + gn]
                              : Wr[(size_t)(k0 + k) * D_OUT + (gn - D_OUT)]);
      }
      tile[k][n] = val;
    }
    __syncthreads();
#pragma unroll
    for (int j = 0; j < 8; ++j) {          // store: consecutive t -> consecutive k
      int n = 8 * j + (t >> 5), k = t & 31;
      Wt[(size_t)(n0 + n) * KPAD + k0 + k] = tile[k][n];
    }
  } else {
    // degree histogram, grid-stride
    const int md = *mode;
    const int TH = HIST_GS * 256;
    for (int e = (b - WT_TILES) * 256 + t; e < N_EDGES; e += TH) {
      int d = load_idx(ei, md, N_EDGES + e, N_NODES);
      atomicAdd(&deg[d], 1);
    }
  }
}

// ---------------- GEMM: xf[M][512] = x[M][.](fp32) @ Wt^T (bf16 MFMA) -------
// 128x128 tile, BK=32, 16x16x32 mfma, 4 waves each 64x64.
// A: reg-staged fp32 + cvt_pk_bf16 + swizzled ds_write; next-K loads
//    prefetched under the MFMA phase.
// B: gl_lds with pre-swizzled global source (LDS dest linear).
// Grid: 1D XCD-grouped; id%8 == m%8 so the 4 N-siblings of an M-panel run
// on one XCD and share the 540KB A-panel via its L2.
__global__ __launch_bounds__(256) void k_gemm(const float* __restrict__ x,
                                              const unsigned short* __restrict__ Wt,
                                              unsigned short* __restrict__ xf, int M) {
  __shared__ unsigned short smem[9216];   // As[0,4096) Bs[4096,8192); Cs overlays 128x72
  unsigned short* As = smem;
  unsigned short* Bs = smem + 4096;
  unsigned short* Cs = smem;

  // XCD-grouped decode: b%8 = XCD = m%8; r = b/8: n = r&3, mq = r>>2.
  const int b = (int)blockIdx.x;
  const int xcd = b & 7, r = b >> 3;
  const int nt4 = r & 3, mq = r >> 2;
  const int m = mq * 8 + xcd;
  if (m >= M_TILES) return;
  const int m0 = m * 128, n0 = nt4 * 128;

  const int tid = threadIdx.x;
  const int w = tid >> 6, lane = tid & 63;
  const int wm = (w >> 1) * 64, wn = (w & 1) * 64;

  f32x4 zero = {0.f, 0.f, 0.f, 0.f};
  const float4 fz = {0.f, 0.f, 0.f, 0.f};
  f32x4 acc[4][4];
#pragma unroll
  for (int i = 0; i < 4; ++i)
#pragma unroll
    for (int j = 0; j < 4; ++j) acc[i][j] = zero;

  const int lrow = lane >> 2, lch = lane & 3;  // 16 rows x 4 x16B chunks / call
  const int swz = lch ^ (lrow & 3);            // chunk-pos XOR swizzle

  float4 f[4];
#define LOADA(K0)                                                         \
  {                                                                       \
    int gka = (K0) + lch * 8;                                             \
    _Pragma("unroll")                                                     \
    for (int j = 0; j < 2; ++j) {                                         \
      int gm = m0 + w * 32 + j * 16 + lrow;                               \
      if (gm >= M) gm = M - 1;                                            \
      const float* gp = x + (size_t)gm * D_IN + gka;                      \
      f[2 * j]     = (gka     < D_IN) ? *(const float4*)gp       : fz;    \
      f[2 * j + 1] = (gka + 4 < D_IN) ? *(const float4*)(gp + 4) : fz;    \
    }                                                                     \
  }

  LOADA(0);
  for (int k0 = 0; k0 < KPAD; k0 += 32) {
    __syncthreads();                          // prev tile fully consumed
    // A: cvt prefetched regs -> swizzled LDS chunk position
#pragma unroll
    for (int j = 0; j < 2; ++j) {
      uint4 pk;
      pk.x = cvt_pk_bf16(f[2 * j].x,     f[2 * j].y);
      pk.y = cvt_pk_bf16(f[2 * j].z,     f[2 * j].w);
      pk.z = cvt_pk_bf16(f[2 * j + 1].x, f[2 * j + 1].y);
      pk.w = cvt_pk_bf16(f[2 * j + 1].z, f[2 * j + 1].w);
      *(uint4*)&As[(w * 32 + j * 16 + lrow) * 32 + swz * 8] = pk;
    }
    // B: gl_lds, pre-swizzled global source (dest linear: lane l -> chunk l&3)
#pragma unroll
    for (int j = 0; j < 2; ++j) {
      int gn = n0 + w * 32 + j * 16 + lrow;
      const char* g = (const char*)Wt + ((size_t)gn * KPAD + k0) * 2 + swz * 16;
      gl_lds16(g, &Bs[(w * 32 + j * 16) * 32]);
    }
    __syncthreads();                          // tile ready (drains gl_lds)
    if (k0 + 32 < KPAD) LOADA(k0 + 32);       // prefetch: flies under MFMA phase

    bf16x8 af[4], bfr[4];
    const int rdsw = ((lane >> 4) ^ (lane & 3)) * 8;  // logical chunk lane>>4
#pragma unroll
    for (int t = 0; t < 4; ++t)
      af[t] = *(const bf16x8*)&As[(wm + t * 16 + (lane & 15)) * 32 + rdsw];
#pragma unroll
    for (int t = 0; t < 4; ++t)
      bfr[t] = *(const bf16x8*)&Bs[(wn + t * 16 + (lane & 15)) * 32 + rdsw];
#pragma unroll
    for (int mt = 0; mt < 4; ++mt)
#pragma unroll
      for (int nt = 0; nt < 4; ++nt)
        acc[mt][nt] = __builtin_amdgcn_mfma_f32_16x16x32_bf16(af[mt], bfr[nt], acc[mt][nt], 0, 0, 0);
  }
#undef LOADA

  // Epilogue: two 64-col passes through Cs[128][72] (16B-aligned rows).
  // C/D layout: col = lane&15, row = (lane>>4)*4 + r.
  __syncthreads();  // all As/Bs reads done before Cs overlay
  {
    const int col = lane & 15, rq = (lane >> 4) * 4;
#pragma unroll
    for (int h = 0; h < 2; ++h) {
      if ((w & 1) == h) {                     // waves with wn == h*64
#pragma unroll
        for (int mt = 0; mt < 4; ++mt)
#pragma unroll
          for (int nt = 0; nt < 4; ++nt)
#pragma unroll
            for (int r2 = 0; r2 < 4; ++r2)
              Cs[(wm + mt * 16 + rq + r2) * 72 + nt * 16 + col] = f2bf(acc[mt][nt][r2]);
      }
      __syncthreads();
      {
        const int row = tid >> 1, seg = tid & 1;  // 2 threads per row, 64B each
        int gm = m0 + row;
        if (gm < M) {
          unsigned short* dst = xf + (size_t)gm * NB + n0 + h * 64 + seg * 32;
          const unsigned short* srcp = &Cs[row * 72 + seg * 32];
#pragma unroll
          for (int jj = 0; jj < 4; ++jj)
            *(uint4*)(dst + jj * 8) = *(const uint4*)(srcp + jj * 8);
        }
      }
      if (h == 0) __syncthreads();            // Cs reused by pass 1
    }
  }
}

// ---------------- 3-phase single-block exclusive scan (n=50000) --------------
__global__ __launch_bounds__(1024) void k_scan(const int* __restrict__ deg,
    int* __restrict__ rowstart, int* __restrict__ cursor, int n) {
  const int t = (int)threadIdx.x;
  const int lane = t & 63, wid = t >> 6;
  const int seg = (n + 1023) / 1024;   // 49
  const int base = t * seg;
  __shared__ int wsum[16];

  int sum = 0;
  for (int j = 0; j < seg; ++j) { int i = base + j; if (i < n) sum += deg[i]; }

  int x = sum;                                    // wave inclusive scan
#pragma unroll
  for (int off = 1; off < 64; off <<= 1) {
    int y = __shfl_up(x, off, 64);
    if (lane >= off) x += y;
  }
  if (lane == 63) wsum[wid] = x;
  __syncthreads();
  if (t < 16) {                                   // exclusive scan of 16 wave sums
    int v = wsum[t], s = v;
#pragma unroll
    for (int off = 1; off < 16; off <<= 1) {
      int y = __shfl_up(s, off, 16);
      if (t >= off) s += y;
    }
    wsum[t] = s - v;
  }
  __syncthreads();
  int run = wsum[wid] + (x - sum);                // exclusive prefix for thread t
  for (int j = 0; j < seg; ++j) {
    int i = base + j;
    if (i < n) { rowstart[i] = run; cursor[i] = run; run += deg[i]; }
  }
  if (t == 1023) rowstart[n] = run;
}

__global__ __launch_bounds__(256) void k_scatter(const int* __restrict__ ei,
                          const int* __restrict__ mode,
                          int* __restrict__ cursor, int* __restrict__ ssrc) {
  const int md = *mode;
  const int TH = SCAT_GS * 256;
  for (int e = (int)blockIdx.x * 256 + (int)threadIdx.x; e < N_EDGES; e += TH) {
    int s = load_idx(ei, md, e, N_NODES);
    int d = load_idx(ei, md, N_EDGES + e, N_NODES);
    int pos = atomicAdd(&cursor[d], 1);
    if (pos >= 0 && pos < N_EDGES) ssrc[pos] = s;
  }
}

// ---------------- fused gather + online softmax + aggregate ------------------
static __device__ __forceinline__ void unpack8(uint4 u, float* v) {
  union { unsigned int i; float f; } c;
  c.i = u.x << 16;         v[0] = c.f;
  c.i = u.x & 0xffff0000u; v[1] = c.f;
  c.i = u.y << 16;         v[2] = c.f;
  c.i = u.y & 0xffff0000u; v[3] = c.f;
  c.i = u.z << 16;         v[4] = c.f;
  c.i = u.z & 0xffff0000u; v[5] = c.f;
  c.i = u.w << 16;         v[6] = c.f;
  c.i = u.w & 0xffff0000u; v[7] = c.f;
}
static __device__ __forceinline__ float dot8(const float* v, const float* xr, const float* a) {
  float e = 0.f;
#pragma unroll
  for (int d = 0; d < 8; ++d) {
    float t = v[d] + xr[d];
    t = fmaxf(t, 0.2f * t);        // LeakyReLU(0.2): max(t, 0.2t)
    e = fmaf(a[d], t, e);
  }
  return e;
}
static __device__ __forceinline__ float red32(float e) {
#pragma unroll
  for (int off = 1; off < 32; off <<= 1) e += __shfl_xor(e, off, 64);
  return e;
}

__global__ __launch_bounds__(256) void k_gat(const unsigned short* __restrict__ xf,
    const int* __restrict__ rowstart, const int* __restrict__ ssrc,
    const float* __restrict__ att, const float* __restrict__ bias,
    float* __restrict__ out, int n) {
  const int gw = (int)blockIdx.x * 4 + (int)(threadIdx.x >> 6);  // 1 wave/dst
  const int lane = (int)(threadIdx.x & 63);
  const int grp = lane >> 5, gl = lane & 31;
  if (gw >= n) return;

  float a[8];
  {
    float4 A0 = ((const float4*)att)[2 * gl];
    float4 A1 = ((const float4*)att)[2 * gl + 1];
    a[0] = A0.x; a[1] = A0.y; a[2] = A0.z; a[3] = A0.w;
    a[4] = A1.x; a[5] = A1.y; a[6] = A1.z; a[7] = A1.w;
  }
  float xr[8], vs[8];
  unpack8(*(const uint4*)(xf + (size_t)gw * NB + D_OUT + 8 * gl), xr);
  unpack8(*(const uint4*)(xf + (size_t)gw * NB + 8 * gl), vs);   // self row (xl)

  // self-loop into group 0; group 1 starts empty
  float m, l, acc[8];
  {
    float e = red32(dot8(vs, xr, a));
    if (grp == 0) {
      m = e; l = 1.f;
#pragma unroll
      for (int d = 0; d < 8; ++d) acc[d] = vs[d];
    } else {
      m = -1e30f; l = 0.f;
#pragma unroll
      for (int d = 0; d < 8; ++d) acc[d] = 0.f;
    }
  }

  const int end = rowstart[gw + 1];
  int i = rowstart[gw] + grp;                     // group g: edges beg+g, +2, ...
  bool have = i < end;
  uint4 vu;
  if (have) {
    unsigned s = (unsigned)ssrc[i];
    vu = *(const uint4*)(xf + ((size_t)s << 9) + 8 * gl);
  }
  while (have) {
    int i2 = i + 2;
    bool have2 = i2 < end;
    uint4 vu2;
    if (have2) {                                  // depth-2 pipeline: prefetch
      unsigned s2 = (unsigned)ssrc[i2];
      vu2 = *(const uint4*)(xf + ((size_t)s2 << 9) + 8 * gl);
    }
    float v[8];
    unpack8(vu, v);
    float e = red32(dot8(v, xr, a));
    float mn = fmaxf(m, e);
    float sc = __expf(m - mn);
    float p  = __expf(e - mn);
#pragma unroll
    for (int d = 0; d < 8; ++d) acc[d] = fmaf(p, v[d], acc[d] * sc);
    l = fmaf(l, sc, p);
    m = mn;
    vu = vu2; i = i2; have = have2;
  }

  // flash-merge the two groups (lane L and L+32 hold the same dims)
  float mo = __shfl_xor(m, 32, 64);
  float mM = fmaxf(m, mo);
  float sA = __expf(m - mM);
  float lA = l * sA;
  float lS = lA + __shfl_xor(lA, 32, 64);
  float inv = 1.f / lS;
#pragma unroll
  for (int d = 0; d < 8; ++d) {
    float t = acc[d] * sA;
    acc[d] = t + __shfl_xor(t, 32, 64);
  }
  if (grp == 0) {
    float4 B0 = ((const float4*)bias)[2 * gl];
    float4 B1 = ((const float4*)bias)[2 * gl + 1];
    float4 o0, o1;
    o0.x = fmaf(acc[0], inv, B0.x); o0.y = fmaf(acc[1], inv, B0.y);
    o0.z = fmaf(acc[2], inv, B0.z); o0.w = fmaf(acc[3], inv, B0.w);
    o1.x = fmaf(acc[4], inv, B1.x); o1.y = fmaf(acc[5], inv, B1.y);
    o1.z = fmaf(acc[6], inv, B1.z); o1.w = fmaf(acc[7], inv, B1.w);
    ((float4*)out)[(size_t)gw * 64 + 2 * gl] = o0;
    ((float4*)out)[(size_t)gw * 64 + 2 * gl + 1] = o1;
  }
}

// ---------------- launch -----------------------------------------------------
extern "C" void kernel_launch(void* const* d_in, const int* in_sizes, int n_in,
                              void* d_out, int out_size, void* d_ws, size_t ws_size,
                              hipStream_t stream) {
  (void)in_sizes; (void)n_in; (void)out_size; (void)ws_size;
  const float* x   = (const float*)d_in[0];
  const int*   ei  = (const int*)d_in[1];
  const float* Wl  = (const float*)d_in[2];
  const float* Wr  = (const float*)d_in[3];
  const float* att = (const float*)d_in[4];
  const float* bia = (const float*)d_in[5];
  float* out = (float*)d_out;

  const int N = N_NODES;
  const int E = N_EDGES;

  char* ws = (char*)d_ws;
  size_t off = 0;
  unsigned short* xf = (unsigned short*)(ws + off); off += (size_t)N * NB * 2;    //  51.2 MB
  unsigned short* Wt = (unsigned short*)(ws + off); off += (size_t)NB * KPAD * 2; //   1.1 MB
  off = (off + 255) & ~(size_t)255;
  int* deg      = (int*)(ws + off); off += (size_t)N * 4;
  int* mode     = (int*)(ws + off); off += 256;   // adjacent to deg: one memset
  int* rowstart = (int*)(ws + off); off += (size_t)(N + 1) * 4;
  off = (off + 255) & ~(size_t)255;
  int* cursor   = (int*)(ws + off); off += (size_t)N * 4;
  int* ssrc     = (int*)(ws + off); off += (size_t)E * 4;   // total ~60 MB

  hipMemsetAsync(deg, 0, (size_t)N * 4 + 256, stream);      // deg + mode
  k_mode<<<8, 256, 0, stream>>>((const unsigned int*)ei, mode);
  k_prep<<<PREP_BLOCKS, 256, 0, stream>>>(Wl, Wr, ei, mode, Wt, deg);
  k_gemm<<<GEMM_BLOCKS, 256, 0, stream>>>(x, Wt, xf, N);
  k_scan<<<1, 1024, 0, stream>>>(deg, rowstart, cursor, N);
  k_scatter<<<SCAT_GS, 256, 0, stream>>>(ei, mode, cursor, ssrc);
  k_gat<<<(N + 3) / 4, 256, 0, stream>>>(xf, rowstart, ssrc, att, bia, out, N);
}

// Round 8
// 879.382 us; speedup vs baseline: 1.1896x; 1.1788x over previous
//
#include <hip/hip_runtime.h>
#include <hip/hip_bf16.h>
#include <stdint.h>

// GATv2Conv(1028->256, heads=1, self-loops) on gfx950, fp32 in/out.
// Pipeline: prep(x->bf16 pad, W^T->bf16, degree hist) -> bf16 MFMA GEMM
// (gl_lds both operands; xl|xr -> bf16 xf) -> scan -> scatter (CSR) ->
// fused per-dst online-softmax gather.
// R8/R12 post-mortem: fusing x->bf16 into GEMM A-staging (reg-staged) made
// the GEMM latency-bound: 370us @ MfmaUtil 5.8%, invariant to fetch (491->
// 124MB via XCD-grouping) -> the gl_lds structure, not traffic, is what made
// the R2 GEMM ~42us (REST accounting: 847-153-G = 1037-15-370 => G=42).
// R13: restore R2 pipeline verbatim (xb pre-convert + gl_lds GEMM); ONE
// change: k_gat gather pipeline depth 2 -> 3 (two extra 512B gathers in
// flight per group; iter ~150cy VALU vs ~500cy gather latency).

#define N_NODES 50000
#define N_EDGES 1600000
#define D_IN    1028
#define KPAD    1056   // D_IN padded to x32; xb/Wt zero-filled beyond 1028
#define D_OUT   256
#define NB      512    // xf row: cols [0,256)=xl, [256,512)=xr

// k_prep segments
#define X2B_GS     2048                     // grid-stride blocks for x->bf16
#define X2B_TOT    (N_NODES * 264)          // 4-col chunks: 1056/4 = 264 per row
#define WT_TILES   (33 * 8)                 // 32k x 64n tiles: 1056/32=33, 512/64=8
#define HIST_GS    1024                     // grid-stride blocks for degree hist
#define PREP_BLOCKS (X2B_GS + WT_TILES + HIST_GS)
#define SCAT_GS    2048

typedef __bf16 bf16x8 __attribute__((ext_vector_type(8)));
typedef float  f32x4  __attribute__((ext_vector_type(4)));

static __device__ __forceinline__ void gl_lds16(const void* g, void* l) {
  __builtin_amdgcn_global_load_lds(
      (const __attribute__((address_space(1))) unsigned int*)g,
      (__attribute__((address_space(3))) unsigned int*)l, 16, 0, 0);
}
static __device__ __forceinline__ unsigned short f2bf(float f) {
  union { float f; unsigned int i; } c; c.f = f;
  unsigned int r = 0x7fffu + ((c.i >> 16) & 1u);  // round-to-nearest-even
  return (unsigned short)((c.i + r) >> 16);
}

// ---------------- edge_index dtype autodetect --------------------------------
// mode==0 -> int64, mode!=0 -> int32.
__global__ void k_mode(const unsigned int* __restrict__ ei32, int* __restrict__ mode) {
  int t = blockIdx.x * 256 + threadIdx.x;  // 2048 probes
  if (t < 2048 && ei32[2 * t + 1] != 0u) atomicOr(mode, 1);
}

static __device__ __forceinline__ int load_idx(const int* ei, int md, int pos, int n) {
  int v = md ? ei[pos] : (int)((const long long*)ei)[pos];
  return v < 0 ? 0 : (v >= n ? n - 1 : v);
}

// ---------------- fused prep: x->xb bf16 | W->Wt bf16 | degree hist ----------
__global__ __launch_bounds__(256) void k_prep(const float* __restrict__ x,
    const float* __restrict__ Wl, const float* __restrict__ Wr,
    const int* __restrict__ ei, const int* __restrict__ mode,
    unsigned short* __restrict__ xb, unsigned short* __restrict__ Wt,
    int* __restrict__ deg) {
  __shared__ unsigned short tile[32][66];  // pad 66: read-phase bank = k mod 32
  const int b = blockIdx.x, t = threadIdx.x;
  if (b < X2B_GS) {
    // grid-stride over 4-col chunks; 4 independent loads in flight per thread.
    const int TH = X2B_GS * 256;
    for (int c = b * 256 + t; c < X2B_TOT; c += 4 * TH) {
      int cc[4], rw[4], qq[4]; float4 v[4]; bool ld[4];
#pragma unroll
      for (int u = 0; u < 4; ++u) {
        cc[u] = c + u * TH;
        ld[u] = false; rw[u] = 0; qq[u] = 0;
        if (cc[u] < X2B_TOT) {
          rw[u] = cc[u] / 264;              // magic-mul
          qq[u] = cc[u] - rw[u] * 264;
          if (qq[u] < 257) {                // cols [0,1028): real data
            v[u] = *(const float4*)(x + (size_t)rw[u] * D_IN + 4 * qq[u]);
            ld[u] = true;
          }
        }
      }
#pragma unroll
      for (int u = 0; u < 4; ++u) {
        if (cc[u] < X2B_TOT) {
          ushort4 o = {0, 0, 0, 0};
          if (ld[u]) { o.x = f2bf(v[u].x); o.y = f2bf(v[u].y);
                       o.z = f2bf(v[u].z); o.w = f2bf(v[u].w); }
          *(ushort4*)(xb + (size_t)rw[u] * KPAD + 4 * qq[u]) = o;
        }
      }
    }
  } else if (b < X2B_GS + WT_TILES) {
    // LDS-tiled transpose: 32k x 64n tile, both global sides coalesced.
    const int w = b - X2B_GS;
    const int k0 = (w >> 3) * 32, n0 = (w & 7) * 64;
#pragma unroll
    for (int j = 0; j < 8; ++j) {          // load: consecutive t -> consecutive n
      int k = 4 * j + (t >> 6), n = t & 63;
      unsigned short val = 0;
      if (k0 + k < D_IN) {
        int gn = n0 + n;
        val = f2bf(gn < D_OUT ? Wl[(size_t)(k0 + k) * D_OUT + gn]
                              : Wr[(size_t)(k0 + k) * D_OUT + (gn - D_OUT)]);
      }
      tile[k][n] = val;
    }
    __syncthreads();
#pragma unroll
    for (int j = 0; j < 8; ++j) {          // store: consecutive t -> consecutive k
      int n = 8 * j + (t >> 5), k = t & 31;
      Wt[(size_t)(n0 + n) * KPAD + k0 + k] = tile[k][n];
    }
  } else {
    // degree histogram, grid-stride
    const int md = *mode;
    const int TH = HIST_GS * 256;
    for (int e = (b - X2B_GS - WT_TILES) * 256 + t; e < N_EDGES; e += TH) {
      int d = load_idx(ei, md, N_EDGES + e, N_NODES);
      atomicAdd(&deg[d], 1);
    }
  }
}

// ---------------- GEMM: xf[M][512] = xb[M][.] @ Wt^T (bf16 MFMA, bf16 out) ---
// 128x128 tile, BK=32, 16x16x32 mfma, 4 waves each 64x64.
// Epilogue: C tile -> LDS (padded) -> coalesced dwordx4 stores.
__global__ __launch_bounds__(256) void k_gemm(const unsigned short* __restrict__ xb,
                                              const unsigned short* __restrict__ Wt,
                                              unsigned short* __restrict__ xf, int M) {
  __shared__ unsigned short smem[16896];  // As[0,4096) Bs[4096,8192); Cs overlays (128x132)
  unsigned short* As = smem;
  unsigned short* Bs = smem + 4096;
  unsigned short* Cs = smem;
  const int tid = threadIdx.x;
  const int w = tid >> 6, lane = tid & 63;
  const int m0 = blockIdx.x * 128, n0 = blockIdx.y * 128;
  const int wm = (w >> 1) * 64, wn = (w & 1) * 64;

  f32x4 zero = {0.f, 0.f, 0.f, 0.f};
  f32x4 acc[4][4];
#pragma unroll
  for (int i = 0; i < 4; ++i)
#pragma unroll
    for (int j = 0; j < 4; ++j) acc[i][j] = zero;

  const int lrow = lane >> 2, lch = lane & 3;  // 16 rows x 4 x16B chunks / call

  for (int k0 = 0; k0 < KPAD; k0 += 32) {
    __syncthreads();
#pragma unroll
    for (int j = 0; j < 2; ++j) {
      int gm = m0 + w * 32 + j * 16 + lrow;
      if (gm >= M) gm = M - 1;
      const char* g = (const char*)xb + ((size_t)gm * KPAD + k0) * 2 + lch * 16;
      gl_lds16(g, &As[(w * 32 + j * 16) * 32]);
    }
#pragma unroll
    for (int j = 0; j < 2; ++j) {
      int gn = n0 + w * 32 + j * 16 + lrow;
      const char* g = (const char*)Wt + ((size_t)gn * KPAD + k0) * 2 + lch * 16;
      gl_lds16(g, &Bs[(w * 32 + j * 16) * 32]);
    }
    __syncthreads();

    bf16x8 af[4], bfr[4];
#pragma unroll
    for (int t = 0; t < 4; ++t)
      af[t] = *(const bf16x8*)&As[(wm + t * 16 + (lane & 15)) * 32 + (lane >> 4) * 8];
#pragma unroll
    for (int t = 0; t < 4; ++t)
      bfr[t] = *(const bf16x8*)&Bs[(wn + t * 16 + (lane & 15)) * 32 + (lane >> 4) * 8];
#pragma unroll
    for (int mt = 0; mt < 4; ++mt)
#pragma unroll
      for (int nt = 0; nt < 4; ++nt)
        acc[mt][nt] = __builtin_amdgcn_mfma_f32_16x16x32_bf16(af[mt], bfr[nt], acc[mt][nt], 0, 0, 0);
  }

  // C/D layout: col = lane&15, row = (lane>>4)*4 + r
  __syncthreads();  // all As/Bs reads done before Cs overlay
  {
    const int col = lane & 15, rq = (lane >> 4) * 4;
#pragma unroll
    for (int mt = 0; mt < 4; ++mt)
#pragma unroll
      for (int nt = 0; nt < 4; ++nt)
#pragma unroll
        for (int r = 0; r < 4; ++r)
          Cs[(wm + mt * 16 + rq + r) * 132 + wn + nt * 16 + col] = f2bf(acc[mt][nt][r]);
  }
  __syncthreads();
  {
    const int row = tid >> 1, half = tid & 1;  // 2 threads per row, 128B each
    int gm = m0 + row;
    if (gm < M) {
      unsigned short* dst = xf + (size_t)gm * NB + n0 + half * 64;
      const unsigned short* srcp = &Cs[row * 132 + half * 64];
#pragma unroll
      for (int j = 0; j < 8; ++j)
        *(uint4*)(dst + j * 8) = *(const uint4*)(srcp + j * 8);
    }
  }
}

// ---------------- 3-phase single-block exclusive scan (n=50000) --------------
__global__ __launch_bounds__(1024) void k_scan(const int* __restrict__ deg,
    int* __restrict__ rowstart, int* __restrict__ cursor, int n) {
  const int t = (int)threadIdx.x;
  const int lane = t & 63, wid = t >> 6;
  const int seg = (n + 1023) / 1024;   // 49
  const int base = t * seg;
  __shared__ int wsum[16];

  int sum = 0;
  for (int j = 0; j < seg; ++j) { int i = base + j; if (i < n) sum += deg[i]; }

  int x = sum;                                    // wave inclusive scan
#pragma unroll
  for (int off = 1; off < 64; off <<= 1) {
    int y = __shfl_up(x, off, 64);
    if (lane >= off) x += y;
  }
  if (lane == 63) wsum[wid] = x;
  __syncthreads();
  if (t < 16) {                                   // exclusive scan of 16 wave sums
    int v = wsum[t], s = v;
#pragma unroll
    for (int off = 1; off < 16; off <<= 1) {
      int y = __shfl_up(s, off, 16);
      if (t >= off) s += y;
    }
    wsum[t] = s - v;
  }
  __syncthreads();
  int run = wsum[wid] + (x - sum);                // exclusive prefix for thread t
  for (int j = 0; j < seg; ++j) {
    int i = base + j;
    if (i < n) { rowstart[i] = run; cursor[i] = run; run += deg[i]; }
  }
  if (t == 1023) rowstart[n] = run;
}

__global__ __launch_bounds__(256) void k_scatter(const int* __restrict__ ei,
                          const int* __restrict__ mode,
                          int* __restrict__ cursor, int* __restrict__ ssrc) {
  const int md = *mode;
  const int TH = SCAT_GS * 256;
  for (int e = (int)blockIdx.x * 256 + (int)threadIdx.x; e < N_EDGES; e += TH) {
    int s = load_idx(ei, md, e, N_NODES);
    int d = load_idx(ei, md, N_EDGES + e, N_NODES);
    int pos = atomicAdd(&cursor[d], 1);
    if (pos >= 0 && pos < N_EDGES) ssrc[pos] = s;
  }
}

// ---------------- fused gather + online softmax + aggregate ------------------
// Wave = 2 groups x 32 lanes; lane covers dims [8*gl, 8*gl+8). Each group
// processes alternating edges of the same dst; flash-merge at the end.
// R13: depth-3 gather pipeline (va/vb/vc): loads for edges i, i+2, i+4 in
// flight; each iter processes one and issues the i+6 load.
static __device__ __forceinline__ void unpack8(uint4 u, float* v) {
  union { unsigned int i; float f; } c;
  c.i = u.x << 16;         v[0] = c.f;
  c.i = u.x & 0xffff0000u; v[1] = c.f;
  c.i = u.y << 16;         v[2] = c.f;
  c.i = u.y & 0xffff0000u; v[3] = c.f;
  c.i = u.z << 16;         v[4] = c.f;
  c.i = u.z & 0xffff0000u; v[5] = c.f;
  c.i = u.w << 16;         v[6] = c.f;
  c.i = u.w & 0xffff0000u; v[7] = c.f;
}
static __device__ __forceinline__ float dot8(const float* v, const float* xr, const float* a) {
  float e = 0.f;
#pragma unroll
  for (int d = 0; d < 8; ++d) {
    float t = v[d] + xr[d];
    t = fmaxf(t, 0.2f * t);        // LeakyReLU(0.2): max(t, 0.2t)
    e = fmaf(a[d], t, e);
  }
  return e;
}
static __device__ __forceinline__ float red32(float e) {
#pragma unroll
  for (int off = 1; off < 32; off <<= 1) e += __shfl_xor(e, off, 64);
  return e;
}

__global__ __launch_bounds__(256) void k_gat(const unsigned short* __restrict__ xf,
    const int* __restrict__ rowstart, const int* __restrict__ ssrc,
    const float* __restrict__ att, const float* __restrict__ bias,
    float* __restrict__ out, int n) {
  const int gw = (int)blockIdx.x * 4 + (int)(threadIdx.x >> 6);  // 1 wave/dst
  const int lane = (int)(threadIdx.x & 63);
  const int grp = lane >> 5, gl = lane & 31;
  if (gw >= n) return;

  float a[8];
  {
    float4 A0 = ((const float4*)att)[2 * gl];
    float4 A1 = ((const float4*)att)[2 * gl + 1];
    a[0] = A0.x; a[1] = A0.y; a[2] = A0.z; a[3] = A0.w;
    a[4] = A1.x; a[5] = A1.y; a[6] = A1.z; a[7] = A1.w;
  }
  float xr[8], vs[8];
  unpack8(*(const uint4*)(xf + (size_t)gw * NB + D_OUT + 8 * gl), xr);
  unpack8(*(const uint4*)(xf + (size_t)gw * NB + 8 * gl), vs);   // self row (xl)

  // self-loop into group 0; group 1 starts empty
  float m, l, acc[8];
  {
    float e = red32(dot8(vs, xr, a));
    if (grp == 0) {
      m = e; l = 1.f;
#pragma unroll
      for (int d = 0; d < 8; ++d) acc[d] = vs[d];
    } else {
      m = -1e30f; l = 0.f;
#pragma unroll
      for (int d = 0; d < 8; ++d) acc[d] = 0.f;
    }
  }

  const int end = rowstart[gw + 1];
  int i = rowstart[gw] + grp;                     // group g: edges beg+g, +2, ...
  bool h0 = i < end, h1 = i + 2 < end, h2 = i + 4 < end;
  uint4 va, vb, vc;
  if (h0) va = *(const uint4*)(xf + ((size_t)(unsigned)ssrc[i] << 9) + 8 * gl);
  if (h1) vb = *(const uint4*)(xf + ((size_t)(unsigned)ssrc[i + 2] << 9) + 8 * gl);
  if (h2) vc = *(const uint4*)(xf + ((size_t)(unsigned)ssrc[i + 4] << 9) + 8 * gl);
  while (h0) {
    float v[8];
    unpack8(va, v);
    float e = red32(dot8(v, xr, a));
    float mn = fmaxf(m, e);
    float sc = __expf(m - mn);
    float p  = __expf(e - mn);
#pragma unroll
    for (int d = 0; d < 8; ++d) acc[d] = fmaf(p, v[d], acc[d] * sc);
    l = fmaf(l, sc, p);
    m = mn;
    va = vb; vb = vc;                             // shift pipeline
    h0 = h1; h1 = h2;
    int i3 = i + 6;
    h2 = i3 < end;
    if (h2) vc = *(const uint4*)(xf + ((size_t)(unsigned)ssrc[i3] << 9) + 8 * gl);
    i += 2;
  }

  // flash-merge the two groups (lane L and L+32 hold the same dims)
  float mo = __shfl_xor(m, 32, 64);
  float mM = fmaxf(m, mo);
  float sA = __expf(m - mM);
  float lA = l * sA;
  float lS = lA + __shfl_xor(lA, 32, 64);
  float inv = 1.f / lS;
#pragma unroll
  for (int d = 0; d < 8; ++d) {
    float t = acc[d] * sA;
    acc[d] = t + __shfl_xor(t, 32, 64);
  }
  if (grp == 0) {
    float4 B0 = ((const float4*)bias)[2 * gl];
    float4 B1 = ((const float4*)bias)[2 * gl + 1];
    float4 o0, o1;
    o0.x = fmaf(acc[0], inv, B0.x); o0.y = fmaf(acc[1], inv, B0.y);
    o0.z = fmaf(acc[2], inv, B0.z); o0.w = fmaf(acc[3], inv, B0.w);
    o1.x = fmaf(acc[4], inv, B1.x); o1.y = fmaf(acc[5], inv, B1.y);
    o1.z = fmaf(acc[6], inv, B1.z); o1.w = fmaf(acc[7], inv, B1.w);
    ((float4*)out)[(size_t)gw * 64 + 2 * gl] = o0;
    ((float4*)out)[(size_t)gw * 64 + 2 * gl + 1] = o1;
  }
}

// ---------------- launch -----------------------------------------------------
extern "C" void kernel_launch(void* const* d_in, const int* in_sizes, int n_in,
                              void* d_out, int out_size, void* d_ws, size_t ws_size,
                              hipStream_t stream) {
  (void)in_sizes; (void)n_in; (void)out_size; (void)ws_size;
  const float* x   = (const float*)d_in[0];
  const int*   ei  = (const int*)d_in[1];
  const float* Wl  = (const float*)d_in[2];
  const float* Wr  = (const float*)d_in[3];
  const float* att = (const float*)d_in[4];
  const float* bia = (const float*)d_in[5];
  float* out = (float*)d_out;

  const int N = N_NODES;
  const int E = N_EDGES;

  char* ws = (char*)d_ws;
  size_t off = 0;
  unsigned short* xb = (unsigned short*)(ws + off); off += (size_t)N * KPAD * 2;  // 105.6 MB
  unsigned short* xf = (unsigned short*)(ws + off); off += (size_t)N * NB * 2;    //  51.2 MB
  unsigned short* Wt = (unsigned short*)(ws + off); off += (size_t)NB * KPAD * 2; //   1.1 MB
  off = (off + 255) & ~(size_t)255;
  int* deg      = (int*)(ws + off); off += (size_t)N * 4;
  int* mode     = (int*)(ws + off); off += 256;   // adjacent to deg: one memset
  int* rowstart = (int*)(ws + off); off += (size_t)(N + 1) * 4;
  off = (off + 255) & ~(size_t)255;
  int* cursor   = (int*)(ws + off); off += (size_t)N * 4;
  int* ssrc     = (int*)(ws + off); off += (size_t)E * 4;   // total ~165 MB

  hipMemsetAsync(deg, 0, (size_t)N * 4 + 256, stream);      // deg + mode
  k_mode<<<8, 256, 0, stream>>>((const unsigned int*)ei, mode);
  k_prep<<<PREP_BLOCKS, 256, 0, stream>>>(x, Wl, Wr, ei, mode, xb, Wt, deg);
  k_gemm<<<dim3((N + 127) / 128, NB / 128), 256, 0, stream>>>(xb, Wt, xf, N);
  k_scan<<<1, 1024, 0, stream>>>(deg, rowstart, cursor, N);
  k_scatter<<<SCAT_GS, 256, 0, stream>>>(ei, mode, cursor, ssrc);
  k_gat<<<(N + 3) / 4, 256, 0, stream>>>(xf, rowstart, ssrc, att, bia, out, N);
}

// Round 10
// 868.331 us; speedup vs baseline: 1.2047x; 1.0127x over previous
//
#include <hip/hip_runtime.h>
#include <hip/hip_bf16.h>
#include <stdint.h>

// GATv2Conv(1028->256, heads=1, self-loops) on gfx950, fp32 in/out.
// Pipeline: prep(x->bf16 pad, W^T->bf16) | hist -> bf16 MFMA GEMM (gl_lds) ->
// scan -> scatter (CSR) -> fused per-dst online-softmax gather (depth-2).
// R13 post-mortem: gat depth-3 cost ~32us (revert to depth-2); REST ~650us is
// spread across kernels that never surface in top-5 (<152us each). Fused
// k_prep's grid-stride x2b blocks occupy all CUs until done, so x2b and hist
// were already ~serial in one dispatch (153 ~= x2b + hist) -- R6's x2b
// restructuring couldn't move the total if hist atomics are the pole.
// R14: fission k_hist out of k_prep for attribution (cost ~0); revert gat.
// Predict: atomic-theory right -> prep ~60-90us, hist ~80-140us surfaces;
// wrong -> prep ~145us, hist ~15-25us.
// R15: identical resubmit — R14 bench hit GPUAcquisitionTimeout (no data).

#define N_NODES 50000
#define N_EDGES 1600000
#define D_IN    1028
#define KPAD    1056   // D_IN padded to x32; xb/Wt zero-filled beyond 1028
#define D_OUT   256
#define NB      512    // xf row: cols [0,256)=xl, [256,512)=xr

// k_prep segments (x2b + Wt only; hist is its own kernel now)
#define X2B_GS     2048                     // grid-stride blocks for x->bf16
#define X2B_TOT    (N_NODES * 264)          // 4-col chunks: 1056/4 = 264 per row
#define WT_TILES   (33 * 8)                 // 32k x 64n tiles: 1056/32=33, 512/64=8
#define PREP_BLOCKS (X2B_GS + WT_TILES)
#define HIST_GS    1024                     // grid-stride blocks for degree hist
#define SCAT_GS    2048

typedef __bf16 bf16x8 __attribute__((ext_vector_type(8)));
typedef float  f32x4  __attribute__((ext_vector_type(4)));

static __device__ __forceinline__ void gl_lds16(const void* g, void* l) {
  __builtin_amdgcn_global_load_lds(
      (const __attribute__((address_space(1))) unsigned int*)g,
      (__attribute__((address_space(3))) unsigned int*)l, 16, 0, 0);
}
static __device__ __forceinline__ unsigned short f2bf(float f) {
  union { float f; unsigned int i; } c; c.f = f;
  unsigned int r = 0x7fffu + ((c.i >> 16) & 1u);  // round-to-nearest-even
  return (unsigned short)((c.i + r) >> 16);
}

// ---------------- edge_index dtype autodetect --------------------------------
// mode==0 -> int64, mode!=0 -> int32.
__global__ void k_mode(const unsigned int* __restrict__ ei32, int* __restrict__ mode) {
  int t = blockIdx.x * 256 + threadIdx.x;  // 2048 probes
  if (t < 2048 && ei32[2 * t + 1] != 0u) atomicOr(mode, 1);
}

static __device__ __forceinline__ int load_idx(const int* ei, int md, int pos, int n) {
  int v = md ? ei[pos] : (int)((const long long*)ei)[pos];
  return v < 0 ? 0 : (v >= n ? n - 1 : v);
}

// ---------------- prep: x->xb bf16 | W->Wt bf16 ------------------------------
__global__ __launch_bounds__(256) void k_prep(const float* __restrict__ x,
    const float* __restrict__ Wl, const float* __restrict__ Wr,
    unsigned short* __restrict__ xb, unsigned short* __restrict__ Wt) {
  __shared__ unsigned short tile[32][66];  // pad 66: read-phase bank = k mod 32
  const int b = blockIdx.x, t = threadIdx.x;
  if (b < X2B_GS) {
    // grid-stride over 4-col chunks; 4 independent loads in flight per thread.
    const int TH = X2B_GS * 256;
    for (int c = b * 256 + t; c < X2B_TOT; c += 4 * TH) {
      int cc[4], rw[4], qq[4]; float4 v[4]; bool ld[4];
#pragma unroll
      for (int u = 0; u < 4; ++u) {
        cc[u] = c + u * TH;
        ld[u] = false; rw[u] = 0; qq[u] = 0;
        if (cc[u] < X2B_TOT) {
          rw[u] = cc[u] / 264;              // magic-mul
          qq[u] = cc[u] - rw[u] * 264;
          if (qq[u] < 257) {                // cols [0,1028): real data
            v[u] = *(const float4*)(x + (size_t)rw[u] * D_IN + 4 * qq[u]);
            ld[u] = true;
          }
        }
      }
#pragma unroll
      for (int u = 0; u < 4; ++u) {
        if (cc[u] < X2B_TOT) {
          ushort4 o = {0, 0, 0, 0};
          if (ld[u]) { o.x = f2bf(v[u].x); o.y = f2bf(v[u].y);
                       o.z = f2bf(v[u].z); o.w = f2bf(v[u].w); }
          *(ushort4*)(xb + (size_t)rw[u] * KPAD + 4 * qq[u]) = o;
        }
      }
    }
  } else {
    // LDS-tiled transpose: 32k x 64n tile, both global sides coalesced.
    const int w = b - X2B_GS;
    const int k0 = (w >> 3) * 32, n0 = (w & 7) * 64;
#pragma unroll
    for (int j = 0; j < 8; ++j) {          // load: consecutive t -> consecutive n
      int k = 4 * j + (t >> 6), n = t & 63;
      unsigned short val = 0;
      if (k0 + k < D_IN) {
        int gn = n0 + n;
        val = f2bf(gn < D_OUT ? Wl[(size_t)(k0 + k) * D_OUT + gn]
                              : Wr[(size_t)(k0 + k) * D_OUT + (gn - D_OUT)]);
      }
      tile[k][n] = val;
    }
    __syncthreads();
#pragma unroll
    for (int j = 0; j < 8; ++j) {          // store: consecutive t -> consecutive k
      int n = 8 * j + (t >> 5), k = t & 31;
      Wt[(size_t)(n0 + n) * KPAD + k0 + k] = tile[k][n];
    }
  }
}

// ---------------- degree histogram (own dispatch for attribution) ------------
__global__ __launch_bounds__(256) void k_hist(const int* __restrict__ ei,
    const int* __restrict__ mode, int* __restrict__ deg) {
  const int md = *mode;
  const int TH = HIST_GS * 256;
  for (int e = (int)blockIdx.x * 256 + (int)threadIdx.x; e < N_EDGES; e += TH) {
    int d = load_idx(ei, md, N_EDGES + e, N_NODES);
    atomicAdd(&deg[d], 1);
  }
}

// ---------------- GEMM: xf[M][512] = xb[M][.] @ Wt^T (bf16 MFMA, bf16 out) ---
// 128x128 tile, BK=32, 16x16x32 mfma, 4 waves each 64x64.
__global__ __launch_bounds__(256) void k_gemm(const unsigned short* __restrict__ xb,
                                              const unsigned short* __restrict__ Wt,
                                              unsigned short* __restrict__ xf, int M) {
  __shared__ unsigned short smem[16896];  // As[0,4096) Bs[4096,8192); Cs overlays (128x132)
  unsigned short* As = smem;
  unsigned short* Bs = smem + 4096;
  unsigned short* Cs = smem;
  const int tid = threadIdx.x;
  const int w = tid >> 6, lane = tid & 63;
  const int m0 = blockIdx.x * 128, n0 = blockIdx.y * 128;
  const int wm = (w >> 1) * 64, wn = (w & 1) * 64;

  f32x4 zero = {0.f, 0.f, 0.f, 0.f};
  f32x4 acc[4][4];
#pragma unroll
  for (int i = 0; i < 4; ++i)
#pragma unroll
    for (int j = 0; j < 4; ++j) acc[i][j] = zero;

  const int lrow = lane >> 2, lch = lane & 3;  // 16 rows x 4 x16B chunks / call

  for (int k0 = 0; k0 < KPAD; k0 += 32) {
    __syncthreads();
#pragma unroll
    for (int j = 0; j < 2; ++j) {
      int gm = m0 + w * 32 + j * 16 + lrow;
      if (gm >= M) gm = M - 1;
      const char* g = (const char*)xb + ((size_t)gm * KPAD + k0) * 2 + lch * 16;
      gl_lds16(g, &As[(w * 32 + j * 16) * 32]);
    }
#pragma unroll
    for (int j = 0; j < 2; ++j) {
      int gn = n0 + w * 32 + j * 16 + lrow;
      const char* g = (const char*)Wt + ((size_t)gn * KPAD + k0) * 2 + lch * 16;
      gl_lds16(g, &Bs[(w * 32 + j * 16) * 32]);
    }
    __syncthreads();

    bf16x8 af[4], bfr[4];
#pragma unroll
    for (int t = 0; t < 4; ++t)
      af[t] = *(const bf16x8*)&As[(wm + t * 16 + (lane & 15)) * 32 + (lane >> 4) * 8];
#pragma unroll
    for (int t = 0; t < 4; ++t)
      bfr[t] = *(const bf16x8*)&Bs[(wn + t * 16 + (lane & 15)) * 32 + (lane >> 4) * 8];
#pragma unroll
    for (int mt = 0; mt < 4; ++mt)
#pragma unroll
      for (int nt = 0; nt < 4; ++nt)
        acc[mt][nt] = __builtin_amdgcn_mfma_f32_16x16x32_bf16(af[mt], bfr[nt], acc[mt][nt], 0, 0, 0);
  }

  // C/D layout: col = lane&15, row = (lane>>4)*4 + r
  __syncthreads();  // all As/Bs reads done before Cs overlay
  {
    const int col = lane & 15, rq = (lane >> 4) * 4;
#pragma unroll
    for (int mt = 0; mt < 4; ++mt)
#pragma unroll
      for (int nt = 0; nt < 4; ++nt)
#pragma unroll
        for (int r = 0; r < 4; ++r)
          Cs[(wm + mt * 16 + rq + r) * 132 + wn + nt * 16 + col] = f2bf(acc[mt][nt][r]);
  }
  __syncthreads();
  {
    const int row = tid >> 1, half = tid & 1;  // 2 threads per row, 128B each
    int gm = m0 + row;
    if (gm < M) {
      unsigned short* dst = xf + (size_t)gm * NB + n0 + half * 64;
      const unsigned short* srcp = &Cs[row * 132 + half * 64];
#pragma unroll
      for (int j = 0; j < 8; ++j)
        *(uint4*)(dst + j * 8) = *(const uint4*)(srcp + j * 8);
    }
  }
}

// ---------------- 3-phase single-block exclusive scan (n=50000) --------------
__global__ __launch_bounds__(1024) void k_scan(const int* __restrict__ deg,
    int* __restrict__ rowstart, int* __restrict__ cursor, int n) {
  const int t = (int)threadIdx.x;
  const int lane = t & 63, wid = t >> 6;
  const int seg = (n + 1023) / 1024;   // 49
  const int base = t * seg;
  __shared__ int wsum[16];

  int sum = 0;
  for (int j = 0; j < seg; ++j) { int i = base + j; if (i < n) sum += deg[i]; }

  int x = sum;                                    // wave inclusive scan
#pragma unroll
  for (int off = 1; off < 64; off <<= 1) {
    int y = __shfl_up(x, off, 64);
    if (lane >= off) x += y;
  }
  if (lane == 63) wsum[wid] = x;
  __syncthreads();
  if (t < 16) {                                   // exclusive scan of 16 wave sums
    int v = wsum[t], s = v;
#pragma unroll
    for (int off = 1; off < 16; off <<= 1) {
      int y = __shfl_up(s, off, 16);
      if (t >= off) s += y;
    }
    wsum[t] = s - v;
  }
  __syncthreads();
  int run = wsum[wid] + (x - sum);                // exclusive prefix for thread t
  for (int j = 0; j < seg; ++j) {
    int i = base + j;
    if (i < n) { rowstart[i] = run; cursor[i] = run; run += deg[i]; }
  }
  if (t == 1023) rowstart[n] = run;
}

__global__ __launch_bounds__(256) void k_scatter(const int* __restrict__ ei,
                          const int* __restrict__ mode,
                          int* __restrict__ cursor, int* __restrict__ ssrc) {
  const int md = *mode;
  const int TH = SCAT_GS * 256;
  for (int e = (int)blockIdx.x * 256 + (int)threadIdx.x; e < N_EDGES; e += TH) {
    int s = load_idx(ei, md, e, N_NODES);
    int d = load_idx(ei, md, N_EDGES + e, N_NODES);
    int pos = atomicAdd(&cursor[d], 1);
    if (pos >= 0 && pos < N_EDGES) ssrc[pos] = s;
  }
}

// ---------------- fused gather + online softmax + aggregate ------------------
// Wave = 2 groups x 32 lanes; lane covers dims [8*gl, 8*gl+8). Each group
// processes alternating edges of the same dst; flash-merge at the end.
static __device__ __forceinline__ void unpack8(uint4 u, float* v) {
  union { unsigned int i; float f; } c;
  c.i = u.x << 16;         v[0] = c.f;
  c.i = u.x & 0xffff0000u; v[1] = c.f;
  c.i = u.y << 16;         v[2] = c.f;
  c.i = u.y & 0xffff0000u; v[3] = c.f;
  c.i = u.z << 16;         v[4] = c.f;
  c.i = u.z & 0xffff0000u; v[5] = c.f;
  c.i = u.w << 16;         v[6] = c.f;
  c.i = u.w & 0xffff0000u; v[7] = c.f;
}
static __device__ __forceinline__ float dot8(const float* v, const float* xr, const float* a) {
  float e = 0.f;
#pragma unroll
  for (int d = 0; d < 8; ++d) {
    float t = v[d] + xr[d];
    t = fmaxf(t, 0.2f * t);        // LeakyReLU(0.2): max(t, 0.2t)
    e = fmaf(a[d], t, e);
  }
  return e;
}
static __device__ __forceinline__ float red32(float e) {
#pragma unroll
  for (int off = 1; off < 32; off <<= 1) e += __shfl_xor(e, off, 64);
  return e;
}

__global__ __launch_bounds__(256) void k_gat(const unsigned short* __restrict__ xf,
    const int* __restrict__ rowstart, const int* __restrict__ ssrc,
    const float* __restrict__ att, const float* __restrict__ bias,
    float* __restrict__ out, int n) {
  const int gw = (int)blockIdx.x * 4 + (int)(threadIdx.x >> 6);  // 1 wave/dst
  const int lane = (int)(threadIdx.x & 63);
  const int grp = lane >> 5, gl = lane & 31;
  if (gw >= n) return;

  float a[8];
  {
    float4 A0 = ((const float4*)att)[2 * gl];
    float4 A1 = ((const float4*)att)[2 * gl + 1];
    a[0] = A0.x; a[1] = A0.y; a[2] = A0.z; a[3] = A0.w;
    a[4] = A1.x; a[5] = A1.y; a[6] = A1.z; a[7] = A1.w;
  }
  float xr[8], vs[8];
  unpack8(*(const uint4*)(xf + (size_t)gw * NB + D_OUT + 8 * gl), xr);
  unpack8(*(const uint4*)(xf + (size_t)gw * NB + 8 * gl), vs);   // self row (xl)

  // self-loop into group 0; group 1 starts empty
  float m, l, acc[8];
  {
    float e = red32(dot8(vs, xr, a));
    if (grp == 0) {
      m = e; l = 1.f;
#pragma unroll
      for (int d = 0; d < 8; ++d) acc[d] = vs[d];
    } else {
      m = -1e30f; l = 0.f;
#pragma unroll
      for (int d = 0; d < 8; ++d) acc[d] = 0.f;
    }
  }

  const int end = rowstart[gw + 1];
  int i = rowstart[gw] + grp;                     // group g: edges beg+g, +2, ...
  bool have = i < end;
  uint4 vu;
  if (have) {
    unsigned s = (unsigned)ssrc[i];
    vu = *(const uint4*)(xf + ((size_t)s << 9) + 8 * gl);
  }
  while (have) {
    int i2 = i + 2;
    bool have2 = i2 < end;
    uint4 vu2;
    if (have2) {                                  // depth-2 pipeline: prefetch
      unsigned s2 = (unsigned)ssrc[i2];
      vu2 = *(const uint4*)(xf + ((size_t)s2 << 9) + 8 * gl);
    }
    float v[8];
    unpack8(vu, v);
    float e = red32(dot8(v, xr, a));
    float mn = fmaxf(m, e);
    float sc = __expf(m - mn);
    float p  = __expf(e - mn);
#pragma unroll
    for (int d = 0; d < 8; ++d) acc[d] = fmaf(p, v[d], acc[d] * sc);
    l = fmaf(l, sc, p);
    m = mn;
    vu = vu2; i = i2; have = have2;
  }

  // flash-merge the two groups (lane L and L+32 hold the same dims)
  float mo = __shfl_xor(m, 32, 64);
  float mM = fmaxf(m, mo);
  float sA = __expf(m - mM);
  float lA = l * sA;
  float lS = lA + __shfl_xor(lA, 32, 64);
  float inv = 1.f / lS;
#pragma unroll
  for (int d = 0; d < 8; ++d) {
    float t = acc[d] * sA;
    acc[d] = t + __shfl_xor(t, 32, 64);
  }
  if (grp == 0) {
    float4 B0 = ((const float4*)bias)[2 * gl];
    float4 B1 = ((const float4*)bias)[2 * gl + 1];
    float4 o0, o1;
    o0.x = fmaf(acc[0], inv, B0.x); o0.y = fmaf(acc[1], inv, B0.y);
    o0.z = fmaf(acc[2], inv, B0.z); o0.w = fmaf(acc[3], inv, B0.w);
    o1.x = fmaf(acc[4], inv, B1.x); o1.y = fmaf(acc[5], inv, B1.y);
    o1.z = fmaf(acc[6], inv, B1.z); o1.w = fmaf(acc[7], inv, B1.w);
    ((float4*)out)[(size_t)gw * 64 + 2 * gl] = o0;
    ((float4*)out)[(size_t)gw * 64 + 2 * gl + 1] = o1;
  }
}

// ---------------- launch -----------------------------------------------------
extern "C" void kernel_launch(void* const* d_in, const int* in_sizes, int n_in,
                              void* d_out, int out_size, void* d_ws, size_t ws_size,
                              hipStream_t stream) {
  (void)in_sizes; (void)n_in; (void)out_size; (void)ws_size;
  const float* x   = (const float*)d_in[0];
  const int*   ei  = (const int*)d_in[1];
  const float* Wl  = (const float*)d_in[2];
  const float* Wr  = (const float*)d_in[3];
  const float* att = (const float*)d_in[4];
  const float* bia = (const float*)d_in[5];
  float* out = (float*)d_out;

  const int N = N_NODES;
  const int E = N_EDGES;

  char* ws = (char*)d_ws;
  size_t off = 0;
  unsigned short* xb = (unsigned short*)(ws + off); off += (size_t)N * KPAD * 2;  // 105.6 MB
  unsigned short* xf = (unsigned short*)(ws + off); off += (size_t)N * NB * 2;    //  51.2 MB
  unsigned short* Wt = (unsigned short*)(ws + off); off += (size_t)NB * KPAD * 2; //   1.1 MB
  off = (off + 255) & ~(size_t)255;
  int* deg      = (int*)(ws + off); off += (size_t)N * 4;
  int* mode     = (int*)(ws + off); off += 256;   // adjacent to deg: one memset
  int* rowstart = (int*)(ws + off); off += (size_t)(N + 1) * 4;
  off = (off + 255) & ~(size_t)255;
  int* cursor   = (int*)(ws + off); off += (size_t)N * 4;
  int* ssrc     = (int*)(ws + off); off += (size_t)E * 4;   // total ~165 MB

  hipMemsetAsync(deg, 0, (size_t)N * 4 + 256, stream);      // deg + mode
  k_mode<<<8, 256, 0, stream>>>((const unsigned int*)ei, mode);
  k_hist<<<HIST_GS, 256, 0, stream>>>(ei, mode, deg);
  k_prep<<<PREP_BLOCKS, 256, 0, stream>>>(x, Wl, Wr, xb, Wt);
  k_gemm<<<dim3((N + 127) / 128, NB / 128), 256, 0, stream>>>(xb, Wt, xf, N);
  k_scan<<<1, 1024, 0, stream>>>(deg, rowstart, cursor, N);
  k_scatter<<<SCAT_GS, 256, 0, stream>>>(ei, mode, cursor, ssrc);
  k_gat<<<(N + 3) / 4, 256, 0, stream>>>(xf, rowstart, ssrc, att, bia, out, N);
}

// Round 11
// 846.894 us; speedup vs baseline: 1.2352x; 1.0253x over previous
//
#include <hip/hip_runtime.h>
#include <hip/hip_bf16.h>
#include <stdint.h>

// GATv2Conv(1028->256, heads=1, self-loops) on gfx950, fp32 in/out.
// Pipeline: prep(W^T->bf16) -> [GEMM(fp32-A via async gl_lds, cvt at LDS-read)
// + hist overlapped in same dispatch] -> scan -> scatter -> fused gather.
// R14 attribution: flat profile (gat 145 VALU-bound, prep ~120, hist/scatter
// ~60-100, gemm 42) -> wins come from deleting/overlapping passes.
// R16: (1) delete x2b: A staged fp32 by global_load_lds (async, R2-proven
// structure; R8 failed because staging was SYNC, not because of conversion),
// bf16 cvt at frag-read via v_cvt_pk_bf16_f32; 16B-chunk XOR swizzle with
// pre-swizzled GLOBAL source (m173: gl_lds dest must stay linear) -> 2-way
// A-frag reads. K-tail (>=1028) reads a zeroed ws buffer. XCD-grouped decode
// kept from R12 (FETCH 491->124MB proven). (2) hist blocks appended to the
// GEMM grid -> atomic latency hides under GEMM compute.

#define N_NODES 50000
#define N_EDGES 1600000
#define D_IN    1028
#define KPAD    1056   // K padded to x32; tail reads zero-buffer
#define D_OUT   256
#define NB      512    // xf row: cols [0,256)=xl, [256,512)=xr

#define M_TILES 391    // ceil(50000/128)
#define NXCD    8
#define MQ      ((M_TILES + NXCD - 1) / NXCD)     // 49
#define GEMM_MN (NXCD * MQ * 4)                   // 1568 (4 idle)
#define HIST_B  512
#define GEMM_BLOCKS (GEMM_MN + HIST_B)            // 2080

#define WT_TILES   (33 * 8)                 // 32k x 64n tiles
#define SCAT_GS    2048

typedef __bf16 bf16x8 __attribute__((ext_vector_type(8)));
typedef float  f32x4  __attribute__((ext_vector_type(4)));

static __device__ __forceinline__ void gl_lds16(const void* g, void* l) {
  __builtin_amdgcn_global_load_lds(
      (const __attribute__((address_space(1))) unsigned int*)g,
      (__attribute__((address_space(3))) unsigned int*)l, 16, 0, 0);
}
static __device__ __forceinline__ unsigned short f2bf(float f) {
  union { float f; unsigned int i; } c; c.f = f;
  unsigned int r = 0x7fffu + ((c.i >> 16) & 1u);  // round-to-nearest-even
  return (unsigned short)((c.i + r) >> 16);
}
// packed 2xf32 -> 2xbf16 (RNE): D = [bf16(lo) | bf16(hi)<<16]  (validated R8/R12)
static __device__ __forceinline__ unsigned int cvt_pk_bf16(float lo, float hi) {
  unsigned int r;
  asm("v_cvt_pk_bf16_f32 %0, %1, %2" : "=v"(r) : "v"(lo), "v"(hi));
  return r;
}

// ---------------- edge_index dtype autodetect --------------------------------
// mode==0 -> int64, mode!=0 -> int32.
__global__ void k_mode(const unsigned int* __restrict__ ei32, int* __restrict__ mode) {
  int t = blockIdx.x * 256 + threadIdx.x;  // 2048 probes
  if (t < 2048 && ei32[2 * t + 1] != 0u) atomicOr(mode, 1);
}

static __device__ __forceinline__ int load_idx(const int* ei, int md, int pos, int n) {
  int v = md ? ei[pos] : (int)((const long long*)ei)[pos];
  return v < 0 ? 0 : (v >= n ? n - 1 : v);
}

// ---------------- prep: W^T -> bf16 (tiny) -----------------------------------
__global__ __launch_bounds__(256) void k_prep(const float* __restrict__ Wl,
    const float* __restrict__ Wr, unsigned short* __restrict__ Wt) {
  __shared__ unsigned short tile[32][66];
  const int b = blockIdx.x, t = threadIdx.x;
  const int k0 = (b >> 3) * 32, n0 = (b & 7) * 64;
#pragma unroll
  for (int j = 0; j < 8; ++j) {          // load: consecutive t -> consecutive n
    int k = 4 * j + (t >> 6), n = t & 63;
    unsigned short val = 0;
    if (k0 + k < D_IN) {
      int gn = n0 + n;
      val = f2bf(gn < D_OUT ? Wl[(size_t)(k0 + k) * D_OUT + gn]
                            : Wr[(size_t)(k0 + k) * D_OUT + (gn - D_OUT)]);
    }
    tile[k][n] = val;
  }
  __syncthreads();
#pragma unroll
  for (int j = 0; j < 8; ++j) {          // store: consecutive t -> consecutive k
    int n = 8 * j + (t >> 5), k = t & 31;
    Wt[(size_t)(n0 + n) * KPAD + k0 + k] = tile[k][n];
  }
}

// ---------------- GEMM (fp32 A, async) + overlapped degree hist --------------
// 128x128 tile, BK=32, 16x16x32 mfma, 4 waves each 64x64.
// A: gl_lds of fp32 x, source k-chunks XOR-swizzled (c_log = c_phys ^ (row&7)),
//    LDS [128][32]f32 linear; frag-read applies same XOR -> 2-way max;
//    bf16 conversion via cvt_pk at read. B: gl_lds of bf16 Wt (unchanged).
// Blocks >= GEMM_MN run the degree histogram (independent work, overlaps).
__global__ __launch_bounds__(256) void k_gemm(const float* __restrict__ x,
    const unsigned short* __restrict__ Wt, unsigned short* __restrict__ xf, int M,
    const int* __restrict__ ei, const int* __restrict__ mode,
    int* __restrict__ deg, const float* __restrict__ zbuf) {
  const int bid = (int)blockIdx.x;
  if (bid >= GEMM_MN) {                   // ---- overlapped histogram ----
    const int md = *mode;
    const int TH = HIST_B * 256;
    for (int e = (bid - GEMM_MN) * 256 + (int)threadIdx.x; e < N_EDGES; e += TH) {
      int d = load_idx(ei, md, N_EDGES + e, N_NODES);
      atomicAdd(&deg[d], 1);
    }
    return;
  }
  // XCD-grouped decode (R12): b&7 = xcd = m%8 -> 4 N-siblings share one L2.
  const int xcd = bid & 7, r = bid >> 3;
  const int nt4 = r & 3, mq = r >> 2;
  const int m = mq * 8 + xcd;
  if (m >= M_TILES) return;
  const int m0 = m * 128, n0 = nt4 * 128;

  __shared__ unsigned short smem[16896];  // 33792B: Asf 16KB | Bs 8KB; Cs overlay
  float* Asf = (float*)smem;              // [128][32] f32, chunk-swizzled
  unsigned short* Bs = smem + 8192;
  unsigned short* Cs = smem;

  const int tid = threadIdx.x;
  const int w = tid >> 6, lane = tid & 63;
  const int wm = (w >> 1) * 64, wn = (w & 1) * 64;

  f32x4 zero = {0.f, 0.f, 0.f, 0.f};
  f32x4 acc[4][4];
#pragma unroll
  for (int i = 0; i < 4; ++i)
#pragma unroll
    for (int j = 0; j < 4; ++j) acc[i][j] = zero;

  const int lrow = lane >> 2, lch = lane & 3;   // B staging: 16 rows x 4 chunks
  const int arow = lane >> 3;                   // A staging: 8 rows x 8 chunks/call
  const int aclog = (lane & 7) ^ (arow & 7);    // pre-swizzled source chunk

  for (int k0 = 0; k0 < KPAD; k0 += 32) {
    __syncthreads();
    // A: 4 calls cover wave's 32 rows x 128B (fp32), source chunk-swizzled
#pragma unroll
    for (int cc = 0; cc < 4; ++cc) {
      int gm = m0 + w * 32 + cc * 8 + arow;
      if (gm >= M) gm = M - 1;
      int k = k0 + aclog * 4;
      const float* src = (k < D_IN) ? (x + (size_t)gm * D_IN + k) : zbuf;
      gl_lds16(src, &Asf[(w * 32) * 32 + cc * 256]);
    }
    // B: bf16 Wt (zero-padded at prep), linear
#pragma unroll
    for (int j = 0; j < 2; ++j) {
      int gn = n0 + w * 32 + j * 16 + lrow;
      const char* g = (const char*)Wt + ((size_t)gn * KPAD + k0) * 2 + lch * 16;
      gl_lds16(g, &Bs[(w * 32 + j * 16) * 32]);
    }
    __syncthreads();                      // vmcnt drained by compiler before barrier

    bf16x8 af[4], bfr[4];
#pragma unroll
    for (int t = 0; t < 4; ++t) {         // A frag: 2x b128 f32 + 4 cvt_pk
      int R = wm + t * 16 + (lane & 15);
      int c0 = (lane >> 4) * 2, s = R & 7;
      float4 a0 = *(const float4*)&Asf[R * 32 + ((c0)     ^ s) * 4];
      float4 a1 = *(const float4*)&Asf[R * 32 + ((c0 + 1) ^ s) * 4];
      uint4 pk;
      pk.x = cvt_pk_bf16(a0.x, a0.y);
      pk.y = cvt_pk_bf16(a0.z, a0.w);
      pk.z = cvt_pk_bf16(a1.x, a1.y);
      pk.w = cvt_pk_bf16(a1.z, a1.w);
      af[t] = *(bf16x8*)&pk;
    }
#pragma unroll
    for (int t = 0; t < 4; ++t)
      bfr[t] = *(const bf16x8*)&Bs[(wn + t * 16 + (lane & 15)) * 32 + (lane >> 4) * 8];
#pragma unroll
    for (int mt = 0; mt < 4; ++mt)
#pragma unroll
      for (int nt = 0; nt < 4; ++nt)
        acc[mt][nt] = __builtin_amdgcn_mfma_f32_16x16x32_bf16(af[mt], bfr[nt], acc[mt][nt], 0, 0, 0);
  }

  // Epilogue: C -> Cs (128x132 pad) -> coalesced dwordx4. col=lane&15,
  // row=(lane>>4)*4+r.
  __syncthreads();
  {
    const int col = lane & 15, rq = (lane >> 4) * 4;
#pragma unroll
    for (int mt = 0; mt < 4; ++mt)
#pragma unroll
      for (int nt = 0; nt < 4; ++nt)
#pragma unroll
        for (int r2 = 0; r2 < 4; ++r2)
          Cs[(wm + mt * 16 + rq + r2) * 132 + wn + nt * 16 + col] = f2bf(acc[mt][nt][r2]);
  }
  __syncthreads();
  {
    const int row = tid >> 1, half = tid & 1;
    int gm = m0 + row;
    if (gm < M) {
      unsigned short* dst = xf + (size_t)gm * NB + n0 + half * 64;
      const unsigned short* srcp = &Cs[row * 132 + half * 64];
#pragma unroll
      for (int j = 0; j < 8; ++j)
        *(uint4*)(dst + j * 8) = *(const uint4*)(srcp + j * 8);
    }
  }
}

// ---------------- 3-phase single-block exclusive scan (n=50000) --------------
__global__ __launch_bounds__(1024) void k_scan(const int* __restrict__ deg,
    int* __restrict__ rowstart, int* __restrict__ cursor, int n) {
  const int t = (int)threadIdx.x;
  const int lane = t & 63, wid = t >> 6;
  const int seg = (n + 1023) / 1024;   // 49
  const int base = t * seg;
  __shared__ int wsum[16];

  int sum = 0;
  for (int j = 0; j < seg; ++j) { int i = base + j; if (i < n) sum += deg[i]; }

  int x = sum;                                    // wave inclusive scan
#pragma unroll
  for (int off = 1; off < 64; off <<= 1) {
    int y = __shfl_up(x, off, 64);
    if (lane >= off) x += y;
  }
  if (lane == 63) wsum[wid] = x;
  __syncthreads();
  if (t < 16) {                                   // exclusive scan of 16 wave sums
    int v = wsum[t], s = v;
#pragma unroll
    for (int off = 1; off < 16; off <<= 1) {
      int y = __shfl_up(s, off, 16);
      if (t >= off) s += y;
    }
    wsum[t] = s - v;
  }
  __syncthreads();
  int run = wsum[wid] + (x - sum);                // exclusive prefix for thread t
  for (int j = 0; j < seg; ++j) {
    int i = base + j;
    if (i < n) { rowstart[i] = run; cursor[i] = run; run += deg[i]; }
  }
  if (t == 1023) rowstart[n] = run;
}

__global__ __launch_bounds__(256) void k_scatter(const int* __restrict__ ei,
                          const int* __restrict__ mode,
                          int* __restrict__ cursor, int* __restrict__ ssrc) {
  const int md = *mode;
  const int TH = SCAT_GS * 256;
  for (int e = (int)blockIdx.x * 256 + (int)threadIdx.x; e < N_EDGES; e += TH) {
    int s = load_idx(ei, md, e, N_NODES);
    int d = load_idx(ei, md, N_EDGES + e, N_NODES);
    int pos = atomicAdd(&cursor[d], 1);
    if (pos >= 0 && pos < N_EDGES) ssrc[pos] = s;
  }
}

// ---------------- fused gather + online softmax + aggregate ------------------
// Wave = 2 groups x 32 lanes; lane covers dims [8*gl, 8*gl+8); depth-2.
static __device__ __forceinline__ void unpack8(uint4 u, float* v) {
  union { unsigned int i; float f; } c;
  c.i = u.x << 16;         v[0] = c.f;
  c.i = u.x & 0xffff0000u; v[1] = c.f;
  c.i = u.y << 16;         v[2] = c.f;
  c.i = u.y & 0xffff0000u; v[3] = c.f;
  c.i = u.z << 16;         v[4] = c.f;
  c.i = u.z & 0xffff0000u; v[5] = c.f;
  c.i = u.w << 16;         v[6] = c.f;
  c.i = u.w & 0xffff0000u; v[7] = c.f;
}
static __device__ __forceinline__ float dot8(const float* v, const float* xr, const float* a) {
  float e = 0.f;
#pragma unroll
  for (int d = 0; d < 8; ++d) {
    float t = v[d] + xr[d];
    t = fmaxf(t, 0.2f * t);        // LeakyReLU(0.2)
    e = fmaf(a[d], t, e);
  }
  return e;
}
static __device__ __forceinline__ float red32(float e) {
#pragma unroll
  for (int off = 1; off < 32; off <<= 1) e += __shfl_xor(e, off, 64);
  return e;
}

__global__ __launch_bounds__(256) void k_gat(const unsigned short* __restrict__ xf,
    const int* __restrict__ rowstart, const int* __restrict__ ssrc,
    const float* __restrict__ att, const float* __restrict__ bias,
    float* __restrict__ out, int n) {
  const int gw = (int)blockIdx.x * 4 + (int)(threadIdx.x >> 6);  // 1 wave/dst
  const int lane = (int)(threadIdx.x & 63);
  const int grp = lane >> 5, gl = lane & 31;
  if (gw >= n) return;

  float a[8];
  {
    float4 A0 = ((const float4*)att)[2 * gl];
    float4 A1 = ((const float4*)att)[2 * gl + 1];
    a[0] = A0.x; a[1] = A0.y; a[2] = A0.z; a[3] = A0.w;
    a[4] = A1.x; a[5] = A1.y; a[6] = A1.z; a[7] = A1.w;
  }
  float xr[8], vs[8];
  unpack8(*(const uint4*)(xf + (size_t)gw * NB + D_OUT + 8 * gl), xr);
  unpack8(*(const uint4*)(xf + (size_t)gw * NB + 8 * gl), vs);   // self row (xl)

  float m, l, acc[8];
  {
    float e = red32(dot8(vs, xr, a));
    if (grp == 0) {
      m = e; l = 1.f;
#pragma unroll
      for (int d = 0; d < 8; ++d) acc[d] = vs[d];
    } else {
      m = -1e30f; l = 0.f;
#pragma unroll
      for (int d = 0; d < 8; ++d) acc[d] = 0.f;
    }
  }

  const int end = rowstart[gw + 1];
  int i = rowstart[gw] + grp;
  bool have = i < end;
  uint4 vu;
  if (have) {
    unsigned s = (unsigned)ssrc[i];
    vu = *(const uint4*)(xf + ((size_t)s << 9) + 8 * gl);
  }
  while (have) {
    int i2 = i + 2;
    bool have2 = i2 < end;
    uint4 vu2;
    if (have2) {
      unsigned s2 = (unsigned)ssrc[i2];
      vu2 = *(const uint4*)(xf + ((size_t)s2 << 9) + 8 * gl);
    }
    float v[8];
    unpack8(vu, v);
    float e = red32(dot8(v, xr, a));
    float mn = fmaxf(m, e);
    float sc = __expf(m - mn);
    float p  = __expf(e - mn);
#pragma unroll
    for (int d = 0; d < 8; ++d) acc[d] = fmaf(p, v[d], acc[d] * sc);
    l = fmaf(l, sc, p);
    m = mn;
    vu = vu2; i = i2; have = have2;
  }

  float mo = __shfl_xor(m, 32, 64);
  float mM = fmaxf(m, mo);
  float sA = __expf(m - mM);
  float lA = l * sA;
  float lS = lA + __shfl_xor(lA, 32, 64);
  float inv = 1.f / lS;
#pragma unroll
  for (int d = 0; d < 8; ++d) {
    float t = acc[d] * sA;
    acc[d] = t + __shfl_xor(t, 32, 64);
  }
  if (grp == 0) {
    float4 B0 = ((const float4*)bias)[2 * gl];
    float4 B1 = ((const float4*)bias)[2 * gl + 1];
    float4 o0, o1;
    o0.x = fmaf(acc[0], inv, B0.x); o0.y = fmaf(acc[1], inv, B0.y);
    o0.z = fmaf(acc[2], inv, B0.z); o0.w = fmaf(acc[3], inv, B0.w);
    o1.x = fmaf(acc[4], inv, B1.x); o1.y = fmaf(acc[5], inv, B1.y);
    o1.z = fmaf(acc[6], inv, B1.z); o1.w = fmaf(acc[7], inv, B1.w);
    ((float4*)out)[(size_t)gw * 64 + 2 * gl] = o0;
    ((float4*)out)[(size_t)gw * 64 + 2 * gl + 1] = o1;
  }
}

// ---------------- launch -----------------------------------------------------
extern "C" void kernel_launch(void* const* d_in, const int* in_sizes, int n_in,
                              void* d_out, int out_size, void* d_ws, size_t ws_size,
                              hipStream_t stream) {
  (void)in_sizes; (void)n_in; (void)out_size; (void)ws_size;
  const float* x   = (const float*)d_in[0];
  const int*   ei  = (const int*)d_in[1];
  const float* Wl  = (const float*)d_in[2];
  const float* Wr  = (const float*)d_in[3];
  const float* att = (const float*)d_in[4];
  const float* bia = (const float*)d_in[5];
  float* out = (float*)d_out;

  const int N = N_NODES;
  const int E = N_EDGES;

  char* ws = (char*)d_ws;
  size_t off = 0;
  unsigned short* xf = (unsigned short*)(ws + off); off += (size_t)N * NB * 2;    //  51.2 MB
  unsigned short* Wt = (unsigned short*)(ws + off); off += (size_t)NB * KPAD * 2; //   1.1 MB
  off = (off + 255) & ~(size_t)255;
  int* deg      = (int*)(ws + off); off += (size_t)N * 4;
  int* mode     = (int*)(ws + off); off += 256;   // one memset covers deg+mode+zbuf
  float* zbuf   = (float*)(ws + off); off += 256; // zeroed 16B+ for GEMM K-tail
  int* rowstart = (int*)(ws + off); off += (size_t)(N + 1) * 4;
  off = (off + 255) & ~(size_t)255;
  int* cursor   = (int*)(ws + off); off += (size_t)N * 4;
  int* ssrc     = (int*)(ws + off); off += (size_t)E * 4;   // total ~60 MB

  hipMemsetAsync(deg, 0, (size_t)N * 4 + 512, stream);      // deg + mode + zbuf
  k_mode<<<8, 256, 0, stream>>>((const unsigned int*)ei, mode);
  k_prep<<<WT_TILES, 256, 0, stream>>>(Wl, Wr, Wt);
  k_gemm<<<GEMM_BLOCKS, 256, 0, stream>>>(x, Wt, xf, N, ei, mode, deg, zbuf);
  k_scan<<<1, 1024, 0, stream>>>(deg, rowstart, cursor, N);
  k_scatter<<<SCAT_GS, 256, 0, stream>>>(ei, mode, cursor, ssrc);
  k_gat<<<(N + 3) / 4, 256, 0, stream>>>(xf, rowstart, ssrc, att, bia, out, N);
}

// Round 12
// 834.412 us; speedup vs baseline: 1.2537x; 1.0150x over previous
//
#include <hip/hip_runtime.h>
#include <hip/hip_bf16.h>
#include <stdint.h>

// GATv2Conv(1028->256, heads=1, self-loops) on gfx950, fp32 in/out.
// Pipeline: prep(W^T->bf16) -> [GEMM(fp32-A async gl_lds, cvt at LDS-read)
// + hist overlapped] -> scan -> scatter -> fused gather.
// R16 post-mortem: fused gemm 232us, MfmaUtil 9.3%, bank-conf 9.9M, occ 30%
// -> barrier-drain-bound: 33 K-steps each draining vmcnt(0) at the barrier
// with nothing in flight during compute. R2 (153 prep + 42 gemm) == R16
// (8 prep + 232 gemm) == 847 total; the fused form is the one with a fix.
// R17: BK 32->64 (KPAD 1088, 17 steps: half the drains, same staging bytes);
// XOR-swizzle B frag path too (R16 left B linear at 128B row stride = 16-way
// -> 9.9M conflicts); pre-swizzled GLOBAL sources, linear gl_lds dests (m173);
// two-pass Cs[128][72] epilogue -> LDS 48KB, 3 blocks/CU.

#define N_NODES 50000
#define N_EDGES 1600000
#define D_IN    1028
#define KPAD    1088   // K padded to x64; A-tail reads zbuf, Wt zero-filled
#define D_OUT   256
#define NB      512    // xf row: cols [0,256)=xl, [256,512)=xr

#define M_TILES 391    // ceil(50000/128)
#define NXCD    8
#define MQ      ((M_TILES + NXCD - 1) / NXCD)     // 49
#define GEMM_MN (NXCD * MQ * 4)                   // 1568 (4 idle)
#define HIST_B  512
#define GEMM_BLOCKS (GEMM_MN + HIST_B)            // 2080

#define WT_TILES   (34 * 8)                 // 1088/32=34 k-tiles x 8 n-tiles
#define SCAT_GS    2048

typedef __bf16 bf16x8 __attribute__((ext_vector_type(8)));
typedef float  f32x4  __attribute__((ext_vector_type(4)));

static __device__ __forceinline__ void gl_lds16(const void* g, void* l) {
  __builtin_amdgcn_global_load_lds(
      (const __attribute__((address_space(1))) unsigned int*)g,
      (__attribute__((address_space(3))) unsigned int*)l, 16, 0, 0);
}
static __device__ __forceinline__ unsigned short f2bf(float f) {
  union { float f; unsigned int i; } c; c.f = f;
  unsigned int r = 0x7fffu + ((c.i >> 16) & 1u);  // round-to-nearest-even
  return (unsigned short)((c.i + r) >> 16);
}
// packed 2xf32 -> 2xbf16 (RNE): D = [bf16(lo) | bf16(hi)<<16]  (validated R8/R12/R16)
static __device__ __forceinline__ unsigned int cvt_pk_bf16(float lo, float hi) {
  unsigned int r;
  asm("v_cvt_pk_bf16_f32 %0, %1, %2" : "=v"(r) : "v"(lo), "v"(hi));
  return r;
}

// ---------------- edge_index dtype autodetect --------------------------------
// mode==0 -> int64, mode!=0 -> int32.
__global__ void k_mode(const unsigned int* __restrict__ ei32, int* __restrict__ mode) {
  int t = blockIdx.x * 256 + threadIdx.x;  // 2048 probes
  if (t < 2048 && ei32[2 * t + 1] != 0u) atomicOr(mode, 1);
}

static __device__ __forceinline__ int load_idx(const int* ei, int md, int pos, int n) {
  int v = md ? ei[pos] : (int)((const long long*)ei)[pos];
  return v < 0 ? 0 : (v >= n ? n - 1 : v);
}

// ---------------- prep: W^T -> bf16 (tiny) -----------------------------------
__global__ __launch_bounds__(256) void k_prep(const float* __restrict__ Wl,
    const float* __restrict__ Wr, unsigned short* __restrict__ Wt) {
  __shared__ unsigned short tile[32][66];
  const int b = blockIdx.x, t = threadIdx.x;
  const int k0 = (b >> 3) * 32, n0 = (b & 7) * 64;
#pragma unroll
  for (int j = 0; j < 8; ++j) {          // load: consecutive t -> consecutive n
    int k = 4 * j + (t >> 6), n = t & 63;
    unsigned short val = 0;
    if (k0 + k < D_IN) {
      int gn = n0 + n;
      val = f2bf(gn < D_OUT ? Wl[(size_t)(k0 + k) * D_OUT + gn]
                            : Wr[(size_t)(k0 + k) * D_OUT + (gn - D_OUT)]);
    }
    tile[k][n] = val;
  }
  __syncthreads();
#pragma unroll
  for (int j = 0; j < 8; ++j) {          // store: consecutive t -> consecutive k
    int n = 8 * j + (t >> 5), k = t & 31;
    Wt[(size_t)(n0 + n) * KPAD + k0 + k] = tile[k][n];
  }
}

// ---------------- GEMM BK=64 (fp32 A, async) + overlapped degree hist --------
// 128x128 tile, BK=64, 16x16x32 mfma (2 K-slices/step), 4 waves each 64x64.
// A: [128][64] f32 LDS; source 16B-chunks XOR-swizzled by (row&15); frag-read
//    applies same XOR -> 2-way. bf16 cvt at read (4 cvt_pk per frag slice).
// B: [128][64] bf16 LDS; source chunks XOR-swizzled by (row&7) -> 2-way.
// Blocks >= GEMM_MN run the degree histogram (independent, overlaps).
__global__ __launch_bounds__(256) void k_gemm(const float* __restrict__ x,
    const unsigned short* __restrict__ Wt, unsigned short* __restrict__ xf, int M,
    const int* __restrict__ ei, const int* __restrict__ mode,
    int* __restrict__ deg, const float* __restrict__ zbuf) {
  const int bid = (int)blockIdx.x;
  if (bid >= GEMM_MN) {                   // ---- overlapped histogram ----
    const int md = *mode;
    const int TH = HIST_B * 256;
    for (int e = (bid - GEMM_MN) * 256 + (int)threadIdx.x; e < N_EDGES; e += TH) {
      int d = load_idx(ei, md, N_EDGES + e, N_NODES);
      atomicAdd(&deg[d], 1);
    }
    return;
  }
  // XCD-grouped decode (R12): bid&7 = xcd = m%8 -> 4 N-siblings share one L2.
  const int xcd = bid & 7, r = bid >> 3;
  const int nt4 = r & 3, mq = r >> 2;
  const int m = mq * 8 + xcd;
  if (m >= M_TILES) return;
  const int m0 = m * 128, n0 = nt4 * 128;

  __shared__ char smem[49152];            // Asf 32KB | Bs 16KB; Cs overlays Asf
  float* Asf = (float*)smem;              // [128][64] f32, chunk-swizzled
  unsigned short* Bs = (unsigned short*)(smem + 32768);  // [128][64] bf16, swz
  unsigned short* Cs = (unsigned short*)smem;            // [128][72] two-pass

  const int tid = threadIdx.x;
  const int w = tid >> 6, lane = tid & 63;
  const int wm = (w >> 1) * 64, wn = (w & 1) * 64;

  f32x4 zero = {0.f, 0.f, 0.f, 0.f};
  f32x4 acc[4][4];
#pragma unroll
  for (int i = 0; i < 4; ++i)
#pragma unroll
    for (int j = 0; j < 4; ++j) acc[i][j] = zero;

  // A staging geometry: call c (0..7): 4 rows x 16 chunks(16B); lane ->
  // row w*32+c*4+(lane>>4), phys chunk lane&15 holds global chunk
  // (lane&15)^((c*4+(lane>>4))&15).
  const int a_r = lane >> 4, a_c = lane & 15;
  // B staging: call c (0..3): 8 rows x 8 chunks; phys chunk lane&7 holds
  // global chunk (lane&7)^((lane>>3)&7)   [c*8 ≡ 0 mod 8].
  const int b_r = lane >> 3, b_c = lane & 7;
  const int b_gc = b_c ^ (b_r & 7);

  for (int k0 = 0; k0 < KPAD; k0 += 64) {
    __syncthreads();
    // A: 8 gl_lds calls cover wave's 32 rows x 256B (fp32)
#pragma unroll
    for (int cc = 0; cc < 8; ++cc) {
      int gm = m0 + w * 32 + cc * 4 + a_r;
      if (gm >= M) gm = M - 1;
      int gc = a_c ^ ((cc * 4 + a_r) & 15);
      int k = k0 + gc * 4;
      const float* src = (k < D_IN) ? (x + (size_t)gm * D_IN + k) : zbuf;
      gl_lds16(src, &Asf[(w * 32 + cc * 4) * 64]);
    }
    // B: 4 gl_lds calls cover wave's 32 rows x 128B (bf16)
#pragma unroll
    for (int cc = 0; cc < 4; ++cc) {
      int gn = n0 + w * 32 + cc * 8 + b_r;
      const unsigned short* src = Wt + (size_t)gn * KPAD + k0 + b_gc * 8;
      gl_lds16(src, &Bs[(w * 32 + cc * 8) * 64]);
    }
    __syncthreads();                      // single drain per 64-wide K-step

#pragma unroll
    for (int s32 = 0; s32 < 2; ++s32) {   // two K=32 slices
      bf16x8 af[4], bfr[4];
#pragma unroll
      for (int t = 0; t < 4; ++t) {       // A frag: 2x b128 f32 + 4 cvt_pk
        int R = wm + t * 16 + (lane & 15);
        int c0 = s32 * 8 + (lane >> 4) * 2, s = R & 15;
        float4 a0 = *(const float4*)&Asf[R * 64 + ((c0)     ^ s) * 4];
        float4 a1 = *(const float4*)&Asf[R * 64 + ((c0 + 1) ^ s) * 4];
        uint4 pk;
        pk.x = cvt_pk_bf16(a0.x, a0.y);
        pk.y = cvt_pk_bf16(a0.z, a0.w);
        pk.z = cvt_pk_bf16(a1.x, a1.y);
        pk.w = cvt_pk_bf16(a1.z, a1.w);
        af[t] = *(bf16x8*)&pk;
      }
#pragma unroll
      for (int t = 0; t < 4; ++t) {       // B frag: 1x b128 (swizzled chunk)
        int R = wn + t * 16 + (lane & 15);
        int c = (s32 * 4 + (lane >> 4)) ^ (R & 7);
        bfr[t] = *(const bf16x8*)&Bs[R * 64 + c * 8];
      }
#pragma unroll
      for (int mt = 0; mt < 4; ++mt)
#pragma unroll
        for (int nt = 0; nt < 4; ++nt)
          acc[mt][nt] = __builtin_amdgcn_mfma_f32_16x16x32_bf16(af[mt], bfr[nt], acc[mt][nt], 0, 0, 0);
    }
  }

  // Epilogue: two 64-col passes through Cs[128][72] (16B-aligned rows).
  // C/D layout: col = lane&15, row = (lane>>4)*4 + r.
  __syncthreads();
  {
    const int col = lane & 15, rq = (lane >> 4) * 4;
#pragma unroll
    for (int h = 0; h < 2; ++h) {
      if ((w & 1) == h) {                 // waves with wn == h*64
#pragma unroll
        for (int mt = 0; mt < 4; ++mt)
#pragma unroll
          for (int nt = 0; nt < 4; ++nt)
#pragma unroll
            for (int r2 = 0; r2 < 4; ++r2)
              Cs[(wm + mt * 16 + rq + r2) * 72 + nt * 16 + col] = f2bf(acc[mt][nt][r2]);
      }
      __syncthreads();
      {
        const int row = tid >> 1, seg = tid & 1;  // 2 threads/row, 64B each
        int gm = m0 + row;
        if (gm < M) {
          unsigned short* dst = xf + (size_t)gm * NB + n0 + h * 64 + seg * 32;
          const unsigned short* srcp = &Cs[row * 72 + seg * 32];
#pragma unroll
          for (int jj = 0; jj < 4; ++jj)
            *(uint4*)(dst + jj * 8) = *(const uint4*)(srcp + jj * 8);
        }
      }
      if (h == 0) __syncthreads();        // Cs reused by pass 1
    }
  }
}

// ---------------- 3-phase single-block exclusive scan (n=50000) --------------
__global__ __launch_bounds__(1024) void k_scan(const int* __restrict__ deg,
    int* __restrict__ rowstart, int* __restrict__ cursor, int n) {
  const int t = (int)threadIdx.x;
  const int lane = t & 63, wid = t >> 6;
  const int seg = (n + 1023) / 1024;   // 49
  const int base = t * seg;
  __shared__ int wsum[16];

  int sum = 0;
  for (int j = 0; j < seg; ++j) { int i = base + j; if (i < n) sum += deg[i]; }

  int x = sum;                                    // wave inclusive scan
#pragma unroll
  for (int off = 1; off < 64; off <<= 1) {
    int y = __shfl_up(x, off, 64);
    if (lane >= off) x += y;
  }
  if (lane == 63) wsum[wid] = x;
  __syncthreads();
  if (t < 16) {                                   // exclusive scan of 16 wave sums
    int v = wsum[t], s = v;
#pragma unroll
    for (int off = 1; off < 16; off <<= 1) {
      int y = __shfl_up(s, off, 16);
      if (t >= off) s += y;
    }
    wsum[t] = s - v;
  }
  __syncthreads();
  int run = wsum[wid] + (x - sum);                // exclusive prefix for thread t
  for (int j = 0; j < seg; ++j) {
    int i = base + j;
    if (i < n) { rowstart[i] = run; cursor[i] = run; run += deg[i]; }
  }
  if (t == 1023) rowstart[n] = run;
}

__global__ __launch_bounds__(256) void k_scatter(const int* __restrict__ ei,
                          const int* __restrict__ mode,
                          int* __restrict__ cursor, int* __restrict__ ssrc) {
  const int md = *mode;
  const int TH = SCAT_GS * 256;
  for (int e = (int)blockIdx.x * 256 + (int)threadIdx.x; e < N_EDGES; e += TH) {
    int s = load_idx(ei, md, e, N_NODES);
    int d = load_idx(ei, md, N_EDGES + e, N_NODES);
    int pos = atomicAdd(&cursor[d], 1);
    if (pos >= 0 && pos < N_EDGES) ssrc[pos] = s;
  }
}

// ---------------- fused gather + online softmax + aggregate ------------------
// Wave = 2 groups x 32 lanes; lane covers dims [8*gl, 8*gl+8); depth-2.
static __device__ __forceinline__ void unpack8(uint4 u, float* v) {
  union { unsigned int i; float f; } c;
  c.i = u.x << 16;         v[0] = c.f;
  c.i = u.x & 0xffff0000u; v[1] = c.f;
  c.i = u.y << 16;         v[2] = c.f;
  c.i = u.y & 0xffff0000u; v[3] = c.f;
  c.i = u.z << 16;         v[4] = c.f;
  c.i = u.z & 0xffff0000u; v[5] = c.f;
  c.i = u.w << 16;         v[6] = c.f;
  c.i = u.w & 0xffff0000u; v[7] = c.f;
}
static __device__ __forceinline__ float dot8(const float* v, const float* xr, const float* a) {
  float e = 0.f;
#pragma unroll
  for (int d = 0; d < 8; ++d) {
    float t = v[d] + xr[d];
    t = fmaxf(t, 0.2f * t);        // LeakyReLU(0.2)
    e = fmaf(a[d], t, e);
  }
  return e;
}
static __device__ __forceinline__ float red32(float e) {
#pragma unroll
  for (int off = 1; off < 32; off <<= 1) e += __shfl_xor(e, off, 64);
  return e;
}

__global__ __launch_bounds__(256) void k_gat(const unsigned short* __restrict__ xf,
    const int* __restrict__ rowstart, const int* __restrict__ ssrc,
    const float* __restrict__ att, const float* __restrict__ bias,
    float* __restrict__ out, int n) {
  const int gw = (int)blockIdx.x * 4 + (int)(threadIdx.x >> 6);  // 1 wave/dst
  const int lane = (int)(threadIdx.x & 63);
  const int grp = lane >> 5, gl = lane & 31;
  if (gw >= n) return;

  float a[8];
  {
    float4 A0 = ((const float4*)att)[2 * gl];
    float4 A1 = ((const float4*)att)[2 * gl + 1];
    a[0] = A0.x; a[1] = A0.y; a[2] = A0.z; a[3] = A0.w;
    a[4] = A1.x; a[5] = A1.y; a[6] = A1.z; a[7] = A1.w;
  }
  float xr[8], vs[8];
  unpack8(*(const uint4*)(xf + (size_t)gw * NB + D_OUT + 8 * gl), xr);
  unpack8(*(const uint4*)(xf + (size_t)gw * NB + 8 * gl), vs);   // self row (xl)

  float m, l, acc[8];
  {
    float e = red32(dot8(vs, xr, a));
    if (grp == 0) {
      m = e; l = 1.f;
#pragma unroll
      for (int d = 0; d < 8; ++d) acc[d] = vs[d];
    } else {
      m = -1e30f; l = 0.f;
#pragma unroll
      for (int d = 0; d < 8; ++d) acc[d] = 0.f;
    }
  }

  const int end = rowstart[gw + 1];
  int i = rowstart[gw] + grp;
  bool have = i < end;
  uint4 vu;
  if (have) {
    unsigned s = (unsigned)ssrc[i];
    vu = *(const uint4*)(xf + ((size_t)s << 9) + 8 * gl);
  }
  while (have) {
    int i2 = i + 2;
    bool have2 = i2 < end;
    uint4 vu2;
    if (have2) {
      unsigned s2 = (unsigned)ssrc[i2];
      vu2 = *(const uint4*)(xf + ((size_t)s2 << 9) + 8 * gl);
    }
    float v[8];
    unpack8(vu, v);
    float e = red32(dot8(v, xr, a));
    float mn = fmaxf(m, e);
    float sc = __expf(m - mn);
    float p  = __expf(e - mn);
#pragma unroll
    for (int d = 0; d < 8; ++d) acc[d] = fmaf(p, v[d], acc[d] * sc);
    l = fmaf(l, sc, p);
    m = mn;
    vu = vu2; i = i2; have = have2;
  }

  float mo = __shfl_xor(m, 32, 64);
  float mM = fmaxf(m, mo);
  float sA = __expf(m - mM);
  float lA = l * sA;
  float lS = lA + __shfl_xor(lA, 32, 64);
  float inv = 1.f / lS;
#pragma unroll
  for (int d = 0; d < 8; ++d) {
    float t = acc[d] * sA;
    acc[d] = t + __shfl_xor(t, 32, 64);
  }
  if (grp == 0) {
    float4 B0 = ((const float4*)bias)[2 * gl];
    float4 B1 = ((const float4*)bias)[2 * gl + 1];
    float4 o0, o1;
    o0.x = fmaf(acc[0], inv, B0.x); o0.y = fmaf(acc[1], inv, B0.y);
    o0.z = fmaf(acc[2], inv, B0.z); o0.w = fmaf(acc[3], inv, B0.w);
    o1.x = fmaf(acc[4], inv, B1.x); o1.y = fmaf(acc[5], inv, B1.y);
    o1.z = fmaf(acc[6], inv, B1.z); o1.w = fmaf(acc[7], inv, B1.w);
    ((float4*)out)[(size_t)gw * 64 + 2 * gl] = o0;
    ((float4*)out)[(size_t)gw * 64 + 2 * gl + 1] = o1;
  }
}

// ---------------- launch -----------------------------------------------------
extern "C" void kernel_launch(void* const* d_in, const int* in_sizes, int n_in,
                              void* d_out, int out_size, void* d_ws, size_t ws_size,
                              hipStream_t stream) {
  (void)in_sizes; (void)n_in; (void)out_size; (void)ws_size;
  const float* x   = (const float*)d_in[0];
  const int*   ei  = (const int*)d_in[1];
  const float* Wl  = (const float*)d_in[2];
  const float* Wr  = (const float*)d_in[3];
  const float* att = (const float*)d_in[4];
  const float* bia = (const float*)d_in[5];
  float* out = (float*)d_out;

  const int N = N_NODES;
  const int E = N_EDGES;

  char* ws = (char*)d_ws;
  size_t off = 0;
  unsigned short* xf = (unsigned short*)(ws + off); off += (size_t)N * NB * 2;    //  51.2 MB
  unsigned short* Wt = (unsigned short*)(ws + off); off += (size_t)NB * KPAD * 2; //   1.1 MB
  off = (off + 255) & ~(size_t)255;
  int* deg      = (int*)(ws + off); off += (size_t)N * 4;
  int* mode     = (int*)(ws + off); off += 256;   // one memset covers deg+mode+zbuf
  float* zbuf   = (float*)(ws + off); off += 256; // zeroed 16B+ for GEMM K-tail
  int* rowstart = (int*)(ws + off); off += (size_t)(N + 1) * 4;
  off = (off + 255) & ~(size_t)255;
  int* cursor   = (int*)(ws + off); off += (size_t)N * 4;
  int* ssrc     = (int*)(ws + off); off += (size_t)E * 4;   // total ~60 MB

  hipMemsetAsync(deg, 0, (size_t)N * 4 + 512, stream);      // deg + mode + zbuf
  k_mode<<<8, 256, 0, stream>>>((const unsigned int*)ei, mode);
  k_prep<<<WT_TILES, 256, 0, stream>>>(Wl, Wr, Wt);
  k_gemm<<<GEMM_BLOCKS, 256, 0, stream>>>(x, Wt, xf, N, ei, mode, deg, zbuf);
  k_scan<<<1, 1024, 0, stream>>>(deg, rowstart, cursor, N);
  k_scatter<<<SCAT_GS, 256, 0, stream>>>(ei, mode, cursor, ssrc);
  k_gat<<<(N + 3) / 4, 256, 0, stream>>>(xf, rowstart, ssrc, att, bia, out, N);
}

// Round 13
// 830.672 us; speedup vs baseline: 1.2593x; 1.0045x over previous
//
#include <hip/hip_runtime.h>
#include <hip/hip_bf16.h>
#include <stdint.h>

// GATv2Conv(1028->256, heads=1, self-loops) on gfx950, fp32 in/out.
// Pipeline: prep(x->bf16 pad | W^T->bf16 | hist, one dispatch, all blocks
// co-resident) -> scan -> [bf16 MFMA GEMM (gl_lds) || scatter (CSR), merged
// dispatch] -> fused per-dst online-softmax gather (defer-rescale).
// R16/R17 post-mortem: fused fp32-A GEMM stuck at 222-370us across 3 variants
// (conflicts 50x-fixed, drains halved: no change) while R2's two-pass xb
// (prep 153 + gemm 42, xb L3-warm) wins -> revert to R2 linear algebra.
// R18: (a) R2 pipeline verbatim; (b) scatter merged INTO gemm dispatch
// (independent work: gemm needs prep, scatter needs scan; atomic-latency vs
// BW bound -> overlap); (c) gat defer-rescale: branch on e<=m (group-uniform)
// saves exp + 8-mul acc rescale on non-max-raising edges.

#define N_NODES 50000
#define N_EDGES 1600000
#define D_IN    1028
#define KPAD    1056   // D_IN padded to x32; xb/Wt zero-filled beyond 1028
#define D_OUT   256
#define NB      512    // xf row: cols [0,256)=xl, [256,512)=xr

// k_prep segments (R2 form: x2b + Wt + hist fused, blocks co-resident)
#define X2B_GS     2048                     // grid-stride blocks for x->bf16
#define X2B_TOT    (N_NODES * 264)          // 4-col chunks: 1056/4 = 264 per row
#define WT_TILES   (33 * 8)                 // 32k x 64n tiles
#define HIST_GS    1024
#define PREP_BLOCKS (X2B_GS + WT_TILES + HIST_GS)

// merged gemm+scatter dispatch
#define M_TILES 391                          // ceil(50000/128)
#define GEMM_MN (M_TILES * 4)                // 1564
#define SCAT_B  2048
#define GS_BLOCKS (GEMM_MN + SCAT_B)         // 3612

typedef __bf16 bf16x8 __attribute__((ext_vector_type(8)));
typedef float  f32x4  __attribute__((ext_vector_type(4)));

static __device__ __forceinline__ void gl_lds16(const void* g, void* l) {
  __builtin_amdgcn_global_load_lds(
      (const __attribute__((address_space(1))) unsigned int*)g,
      (__attribute__((address_space(3))) unsigned int*)l, 16, 0, 0);
}
static __device__ __forceinline__ unsigned short f2bf(float f) {
  union { float f; unsigned int i; } c; c.f = f;
  unsigned int r = 0x7fffu + ((c.i >> 16) & 1u);  // round-to-nearest-even
  return (unsigned short)((c.i + r) >> 16);
}

// ---------------- edge_index dtype autodetect --------------------------------
// mode==0 -> int64, mode!=0 -> int32.
__global__ void k_mode(const unsigned int* __restrict__ ei32, int* __restrict__ mode) {
  int t = blockIdx.x * 256 + threadIdx.x;  // 2048 probes
  if (t < 2048 && ei32[2 * t + 1] != 0u) atomicOr(mode, 1);
}

static __device__ __forceinline__ int load_idx(const int* ei, int md, int pos, int n) {
  int v = md ? ei[pos] : (int)((const long long*)ei)[pos];
  return v < 0 ? 0 : (v >= n ? n - 1 : v);
}

// ---------------- fused prep: x->xb bf16 | W->Wt bf16 | degree hist ----------
__global__ __launch_bounds__(256) void k_prep(const float* __restrict__ x,
    const float* __restrict__ Wl, const float* __restrict__ Wr,
    const int* __restrict__ ei, const int* __restrict__ mode,
    unsigned short* __restrict__ xb, unsigned short* __restrict__ Wt,
    int* __restrict__ deg) {
  __shared__ unsigned short tile[32][66];  // pad 66: read-phase bank = k mod 32
  const int b = blockIdx.x, t = threadIdx.x;
  if (b < X2B_GS) {
    // grid-stride over 4-col chunks; 4 independent loads in flight per thread.
    const int TH = X2B_GS * 256;
    for (int c = b * 256 + t; c < X2B_TOT; c += 4 * TH) {
      int cc[4], rw[4], qq[4]; float4 v[4]; bool ld[4];
#pragma unroll
      for (int u = 0; u < 4; ++u) {
        cc[u] = c + u * TH;
        ld[u] = false; rw[u] = 0; qq[u] = 0;
        if (cc[u] < X2B_TOT) {
          rw[u] = cc[u] / 264;              // magic-mul
          qq[u] = cc[u] - rw[u] * 264;
          if (qq[u] < 257) {                // cols [0,1028): real data
            v[u] = *(const float4*)(x + (size_t)rw[u] * D_IN + 4 * qq[u]);
            ld[u] = true;
          }
        }
      }
#pragma unroll
      for (int u = 0; u < 4; ++u) {
        if (cc[u] < X2B_TOT) {
          ushort4 o = {0, 0, 0, 0};
          if (ld[u]) { o.x = f2bf(v[u].x); o.y = f2bf(v[u].y);
                       o.z = f2bf(v[u].z); o.w = f2bf(v[u].w); }
          *(ushort4*)(xb + (size_t)rw[u] * KPAD + 4 * qq[u]) = o;
        }
      }
    }
  } else if (b < X2B_GS + WT_TILES) {
    // LDS-tiled transpose: 32k x 64n tile, both global sides coalesced.
    const int w = b - X2B_GS;
    const int k0 = (w >> 3) * 32, n0 = (w & 7) * 64;
#pragma unroll
    for (int j = 0; j < 8; ++j) {          // load: consecutive t -> consecutive n
      int k = 4 * j + (t >> 6), n = t & 63;
      unsigned short val = 0;
      if (k0 + k < D_IN) {
        int gn = n0 + n;
        val = f2bf(gn < D_OUT ? Wl[(size_t)(k0 + k) * D_OUT + gn]
                              : Wr[(size_t)(k0 + k) * D_OUT + (gn - D_OUT)]);
      }
      tile[k][n] = val;
    }
    __syncthreads();
#pragma unroll
    for (int j = 0; j < 8; ++j) {          // store: consecutive t -> consecutive k
      int n = 8 * j + (t >> 5), k = t & 31;
      Wt[(size_t)(n0 + n) * KPAD + k0 + k] = tile[k][n];
    }
  } else {
    // degree histogram, grid-stride
    const int md = *mode;
    const int TH = HIST_GS * 256;
    for (int e = (b - X2B_GS - WT_TILES) * 256 + t; e < N_EDGES; e += TH) {
      int d = load_idx(ei, md, N_EDGES + e, N_NODES);
      atomicAdd(&deg[d], 1);
    }
  }
}

// ---------------- GEMM (R2-form, bf16 gl_lds) || scatter ---------------------
// blocks [0,GEMM_MN): 128x128 tile, BK=32, 16x16x32 mfma, 4 waves 64x64 each.
// blocks [GEMM_MN, GS_BLOCKS): CSR scatter (independent; needs scan done).
__global__ __launch_bounds__(256) void k_gemm(const unsigned short* __restrict__ xb,
    const unsigned short* __restrict__ Wt, unsigned short* __restrict__ xf, int M,
    const int* __restrict__ ei, const int* __restrict__ mode,
    int* __restrict__ cursor, int* __restrict__ ssrc) {
  const int bid = (int)blockIdx.x;
  if (bid >= GEMM_MN) {                    // ---- overlapped scatter ----
    const int md = *mode;
    const int TH = SCAT_B * 256;
    for (int e = (bid - GEMM_MN) * 256 + (int)threadIdx.x; e < N_EDGES; e += TH) {
      int s = load_idx(ei, md, e, N_NODES);
      int d = load_idx(ei, md, N_EDGES + e, N_NODES);
      int pos = atomicAdd(&cursor[d], 1);
      if (pos >= 0 && pos < N_EDGES) ssrc[pos] = s;
    }
    return;
  }
  __shared__ unsigned short smem[16896];  // As[0,4096) Bs[4096,8192); Cs overlays
  unsigned short* As = smem;
  unsigned short* Bs = smem + 4096;
  unsigned short* Cs = smem;
  const int tid = threadIdx.x;
  const int w = tid >> 6, lane = tid & 63;
  const int m0 = (bid % M_TILES) * 128, n0 = (bid / M_TILES) * 128;
  const int wm = (w >> 1) * 64, wn = (w & 1) * 64;

  f32x4 zero = {0.f, 0.f, 0.f, 0.f};
  f32x4 acc[4][4];
#pragma unroll
  for (int i = 0; i < 4; ++i)
#pragma unroll
    for (int j = 0; j < 4; ++j) acc[i][j] = zero;

  const int lrow = lane >> 2, lch = lane & 3;  // 16 rows x 4 x16B chunks / call

  for (int k0 = 0; k0 < KPAD; k0 += 32) {
    __syncthreads();
#pragma unroll
    for (int j = 0; j < 2; ++j) {
      int gm = m0 + w * 32 + j * 16 + lrow;
      if (gm >= M) gm = M - 1;
      const char* g = (const char*)xb + ((size_t)gm * KPAD + k0) * 2 + lch * 16;
      gl_lds16(g, &As[(w * 32 + j * 16) * 32]);
    }
#pragma unroll
    for (int j = 0; j < 2; ++j) {
      int gn = n0 + w * 32 + j * 16 + lrow;
      const char* g = (const char*)Wt + ((size_t)gn * KPAD + k0) * 2 + lch * 16;
      gl_lds16(g, &Bs[(w * 32 + j * 16) * 32]);
    }
    __syncthreads();

    bf16x8 af[4], bfr[4];
#pragma unroll
    for (int t = 0; t < 4; ++t)
      af[t] = *(const bf16x8*)&As[(wm + t * 16 + (lane & 15)) * 32 + (lane >> 4) * 8];
#pragma unroll
    for (int t = 0; t < 4; ++t)
      bfr[t] = *(const bf16x8*)&Bs[(wn + t * 16 + (lane & 15)) * 32 + (lane >> 4) * 8];
#pragma unroll
    for (int mt = 0; mt < 4; ++mt)
#pragma unroll
      for (int nt = 0; nt < 4; ++nt)
        acc[mt][nt] = __builtin_amdgcn_mfma_f32_16x16x32_bf16(af[mt], bfr[nt], acc[mt][nt], 0, 0, 0);
  }

  // C/D layout: col = lane&15, row = (lane>>4)*4 + r
  __syncthreads();  // all As/Bs reads done before Cs overlay
  {
    const int col = lane & 15, rq = (lane >> 4) * 4;
#pragma unroll
    for (int mt = 0; mt < 4; ++mt)
#pragma unroll
      for (int nt = 0; nt < 4; ++nt)
#pragma unroll
        for (int r = 0; r < 4; ++r)
          Cs[(wm + mt * 16 + rq + r) * 132 + wn + nt * 16 + col] = f2bf(acc[mt][nt][r]);
  }
  __syncthreads();
  {
    const int row = tid >> 1, half = tid & 1;  // 2 threads per row, 128B each
    int gm = m0 + row;
    if (gm < M) {
      unsigned short* dst = xf + (size_t)gm * NB + n0 + half * 64;
      const unsigned short* srcp = &Cs[row * 132 + half * 64];
#pragma unroll
      for (int j = 0; j < 8; ++j)
        *(uint4*)(dst + j * 8) = *(const uint4*)(srcp + j * 8);
    }
  }
}

// ---------------- 3-phase single-block exclusive scan (n=50000) --------------
__global__ __launch_bounds__(1024) void k_scan(const int* __restrict__ deg,
    int* __restrict__ rowstart, int* __restrict__ cursor, int n) {
  const int t = (int)threadIdx.x;
  const int lane = t & 63, wid = t >> 6;
  const int seg = (n + 1023) / 1024;   // 49
  const int base = t * seg;
  __shared__ int wsum[16];

  int sum = 0;
  for (int j = 0; j < seg; ++j) { int i = base + j; if (i < n) sum += deg[i]; }

  int x = sum;                                    // wave inclusive scan
#pragma unroll
  for (int off = 1; off < 64; off <<= 1) {
    int y = __shfl_up(x, off, 64);
    if (lane >= off) x += y;
  }
  if (lane == 63) wsum[wid] = x;
  __syncthreads();
  if (t < 16) {                                   // exclusive scan of 16 wave sums
    int v = wsum[t], s = v;
#pragma unroll
    for (int off = 1; off < 16; off <<= 1) {
      int y = __shfl_up(s, off, 16);
      if (t >= off) s += y;
    }
    wsum[t] = s - v;
  }
  __syncthreads();
  int run = wsum[wid] + (x - sum);                // exclusive prefix for thread t
  for (int j = 0; j < seg; ++j) {
    int i = base + j;
    if (i < n) { rowstart[i] = run; cursor[i] = run; run += deg[i]; }
  }
  if (t == 1023) rowstart[n] = run;
}

// ---------------- fused gather + online softmax + aggregate ------------------
// Wave = 2 groups x 32 lanes; lane covers dims [8*gl, 8*gl+8); depth-2.
// R18: defer-rescale — e<=m (group-uniform) path skips acc rescale + 1 exp.
static __device__ __forceinline__ void unpack8(uint4 u, float* v) {
  union { unsigned int i; float f; } c;
  c.i = u.x << 16;         v[0] = c.f;
  c.i = u.x & 0xffff0000u; v[1] = c.f;
  c.i = u.y << 16;         v[2] = c.f;
  c.i = u.y & 0xffff0000u; v[3] = c.f;
  c.i = u.z << 16;         v[4] = c.f;
  c.i = u.z & 0xffff0000u; v[5] = c.f;
  c.i = u.w << 16;         v[6] = c.f;
  c.i = u.w & 0xffff0000u; v[7] = c.f;
}
static __device__ __forceinline__ float dot8(const float* v, const float* xr, const float* a) {
  float e = 0.f;
#pragma unroll
  for (int d = 0; d < 8; ++d) {
    float t = v[d] + xr[d];
    t = fmaxf(t, 0.2f * t);        // LeakyReLU(0.2)
    e = fmaf(a[d], t, e);
  }
  return e;
}
static __device__ __forceinline__ float red32(float e) {
#pragma unroll
  for (int off = 1; off < 32; off <<= 1) e += __shfl_xor(e, off, 64);
  return e;
}

__global__ __launch_bounds__(256) void k_gat(const unsigned short* __restrict__ xf,
    const int* __restrict__ rowstart, const int* __restrict__ ssrc,
    const float* __restrict__ att, const float* __restrict__ bias,
    float* __restrict__ out, int n) {
  const int gw = (int)blockIdx.x * 4 + (int)(threadIdx.x >> 6);  // 1 wave/dst
  const int lane = (int)(threadIdx.x & 63);
  const int grp = lane >> 5, gl = lane & 31;
  if (gw >= n) return;

  float a[8];
  {
    float4 A0 = ((const float4*)att)[2 * gl];
    float4 A1 = ((const float4*)att)[2 * gl + 1];
    a[0] = A0.x; a[1] = A0.y; a[2] = A0.z; a[3] = A0.w;
    a[4] = A1.x; a[5] = A1.y; a[6] = A1.z; a[7] = A1.w;
  }
  float xr[8], vs[8];
  unpack8(*(const uint4*)(xf + (size_t)gw * NB + D_OUT + 8 * gl), xr);
  unpack8(*(const uint4*)(xf + (size_t)gw * NB + 8 * gl), vs);   // self row (xl)

  // self-loop into group 0; group 1 starts empty
  float m, l, acc[8];
  {
    float e = red32(dot8(vs, xr, a));
    if (grp == 0) {
      m = e; l = 1.f;
#pragma unroll
      for (int d = 0; d < 8; ++d) acc[d] = vs[d];
    } else {
      m = -1e30f; l = 0.f;
#pragma unroll
      for (int d = 0; d < 8; ++d) acc[d] = 0.f;
    }
  }

  const int end = rowstart[gw + 1];
  int i = rowstart[gw] + grp;                     // group g: edges beg+g, +2, ...
  bool have = i < end;
  uint4 vu;
  if (have) {
    unsigned s = (unsigned)ssrc[i];
    vu = *(const uint4*)(xf + ((size_t)s << 9) + 8 * gl);
  }
  while (have) {
    int i2 = i + 2;
    bool have2 = i2 < end;
    uint4 vu2;
    if (have2) {                                  // depth-2 pipeline: prefetch
      unsigned s2 = (unsigned)ssrc[i2];
      vu2 = *(const uint4*)(xf + ((size_t)s2 << 9) + 8 * gl);
    }
    float v[8];
    unpack8(vu, v);
    float e = red32(dot8(v, xr, a));
    if (e <= m) {                                 // common: max unchanged
      float p = __expf(e - m);
#pragma unroll
      for (int d = 0; d < 8; ++d) acc[d] = fmaf(p, v[d], acc[d]);
      l += p;
    } else {                                      // new max: p = 1
      float sc = __expf(m - e);
#pragma unroll
      for (int d = 0; d < 8; ++d) acc[d] = fmaf(acc[d], sc, v[d]);
      l = fmaf(l, sc, 1.f);
      m = e;
    }
    vu = vu2; i = i2; have = have2;
  }

  // flash-merge the two groups (lane L and L+32 hold the same dims)
  float mo = __shfl_xor(m, 32, 64);
  float mM = fmaxf(m, mo);
  float sA = __expf(m - mM);
  float lA = l * sA;
  float lS = lA + __shfl_xor(lA, 32, 64);
  float inv = 1.f / lS;
#pragma unroll
  for (int d = 0; d < 8; ++d) {
    float t = acc[d] * sA;
    acc[d] = t + __shfl_xor(t, 32, 64);
  }
  if (grp == 0) {
    float4 B0 = ((const float4*)bias)[2 * gl];
    float4 B1 = ((const float4*)bias)[2 * gl + 1];
    float4 o0, o1;
    o0.x = fmaf(acc[0], inv, B0.x); o0.y = fmaf(acc[1], inv, B0.y);
    o0.z = fmaf(acc[2], inv, B0.z); o0.w = fmaf(acc[3], inv, B0.w);
    o1.x = fmaf(acc[4], inv, B1.x); o1.y = fmaf(acc[5], inv, B1.y);
    o1.z = fmaf(acc[6], inv, B1.z); o1.w = fmaf(acc[7], inv, B1.w);
    ((float4*)out)[(size_t)gw * 64 + 2 * gl] = o0;
    ((float4*)out)[(size_t)gw * 64 + 2 * gl + 1] = o1;
  }
}

// ---------------- launch -----------------------------------------------------
extern "C" void kernel_launch(void* const* d_in, const int* in_sizes, int n_in,
                              void* d_out, int out_size, void* d_ws, size_t ws_size,
                              hipStream_t stream) {
  (void)in_sizes; (void)n_in; (void)out_size; (void)ws_size;
  const float* x   = (const float*)d_in[0];
  const int*   ei  = (const int*)d_in[1];
  const float* Wl  = (const float*)d_in[2];
  const float* Wr  = (const float*)d_in[3];
  const float* att = (const float*)d_in[4];
  const float* bia = (const float*)d_in[5];
  float* out = (float*)d_out;

  const int N = N_NODES;
  const int E = N_EDGES;

  char* ws = (char*)d_ws;
  size_t off = 0;
  unsigned short* xb = (unsigned short*)(ws + off); off += (size_t)N * KPAD * 2;  // 105.6 MB
  unsigned short* xf = (unsigned short*)(ws + off); off += (size_t)N * NB * 2;    //  51.2 MB
  unsigned short* Wt = (unsigned short*)(ws + off); off += (size_t)NB * KPAD * 2; //   1.1 MB
  off = (off + 255) & ~(size_t)255;
  int* deg      = (int*)(ws + off); off += (size_t)N * 4;
  int* mode     = (int*)(ws + off); off += 256;   // adjacent to deg: one memset
  int* rowstart = (int*)(ws + off); off += (size_t)(N + 1) * 4;
  off = (off + 255) & ~(size_t)255;
  int* cursor   = (int*)(ws + off); off += (size_t)N * 4;
  int* ssrc     = (int*)(ws + off); off += (size_t)E * 4;   // total ~165 MB

  hipMemsetAsync(deg, 0, (size_t)N * 4 + 256, stream);      // deg + mode
  k_mode<<<8, 256, 0, stream>>>((const unsigned int*)ei, mode);
  k_prep<<<PREP_BLOCKS, 256, 0, stream>>>(x, Wl, Wr, ei, mode, xb, Wt, deg);
  k_scan<<<1, 1024, 0, stream>>>(deg, rowstart, cursor, N);
  k_gemm<<<GS_BLOCKS, 256, 0, stream>>>(xb, Wt, xf, N, ei, mode, cursor, ssrc);
  k_gat<<<(N + 3) / 4, 256, 0, stream>>>(xf, rowstart, ssrc, att, bia, out, N);
}

// Round 14
// 738.984 us; speedup vs baseline: 1.4156x; 1.1241x over previous
//
#include <hip/hip_runtime.h>
#include <hip/hip_bf16.h>
#include <stdint.h>

// GATv2Conv(1028->256, heads=1, self-loops) on gfx950, fp32 in/out.
// Pipeline: prep(hist | x->bf16 | W^T, hist-first so atomics co-resident with
// BW work) -> coalesced 2-kernel scan -> [bf16 MFMA GEMM || scatter merged]
// -> fused per-dst online-softmax gather (defer-rescale).
// R18 post-mortem: total 830 but ledger misses ~250-300us. Suspects: (a)
// single-block k_scan with stride-196B per-thread segments on ONE CU; (b)
// prep = x2b + hist SERIAL (2048 x2b blocks drain before hist starts) -- the
// "x2b invariant 153us" was likely hist's ~100us of atomics all along.
// R19: (1) prep roles reordered hist-first -> hist atomics hide under x2b's
// BW streaming (prep ~= max, not sum); (2) scan -> 196-block coalesced
// partial-sum + apply kernels (LDS Hillis-Steele over block sums).
// Merged gemm+scatter (222us, #1) and gat untouched this round.

#define N_NODES 50000
#define N_EDGES 1600000
#define D_IN    1028
#define KPAD    1056   // D_IN padded to x32; xb/Wt zero-filled beyond 1028
#define D_OUT   256
#define NB      512    // xf row: cols [0,256)=xl, [256,512)=xr

// k_prep segments: hist FIRST (co-resident with x2b), then x2b, then Wt
#define HIST_GS    1024
#define X2B_GS     2048                     // grid-stride blocks for x->bf16
#define X2B_TOT    (N_NODES * 264)          // 4-col chunks: 1056/4 = 264 per row
#define WT_TILES   (33 * 8)                 // 32k x 64n tiles
#define PREP_BLOCKS (HIST_GS + X2B_GS + WT_TILES)

// coalesced scan
#define NBLK ((N_NODES + 255) / 256)        // 196

// merged gemm+scatter dispatch
#define M_TILES 391                          // ceil(50000/128)
#define GEMM_MN (M_TILES * 4)                // 1564
#define SCAT_B  2048
#define GS_BLOCKS (GEMM_MN + SCAT_B)         // 3612

typedef __bf16 bf16x8 __attribute__((ext_vector_type(8)));
typedef float  f32x4  __attribute__((ext_vector_type(4)));

static __device__ __forceinline__ void gl_lds16(const void* g, void* l) {
  __builtin_amdgcn_global_load_lds(
      (const __attribute__((address_space(1))) unsigned int*)g,
      (__attribute__((address_space(3))) unsigned int*)l, 16, 0, 0);
}
static __device__ __forceinline__ unsigned short f2bf(float f) {
  union { float f; unsigned int i; } c; c.f = f;
  unsigned int r = 0x7fffu + ((c.i >> 16) & 1u);  // round-to-nearest-even
  return (unsigned short)((c.i + r) >> 16);
}

// ---------------- edge_index dtype autodetect --------------------------------
// mode==0 -> int64, mode!=0 -> int32.
__global__ void k_mode(const unsigned int* __restrict__ ei32, int* __restrict__ mode) {
  int t = blockIdx.x * 256 + threadIdx.x;  // 2048 probes
  if (t < 2048 && ei32[2 * t + 1] != 0u) atomicOr(mode, 1);
}

static __device__ __forceinline__ int load_idx(const int* ei, int md, int pos, int n) {
  int v = md ? ei[pos] : (int)((const long long*)ei)[pos];
  return v < 0 ? 0 : (v >= n ? n - 1 : v);
}

// ---------------- fused prep: hist | x->xb bf16 | W->Wt bf16 -----------------
__global__ __launch_bounds__(256) void k_prep(const float* __restrict__ x,
    const float* __restrict__ Wl, const float* __restrict__ Wr,
    const int* __restrict__ ei, const int* __restrict__ mode,
    unsigned short* __restrict__ xb, unsigned short* __restrict__ Wt,
    int* __restrict__ deg) {
  __shared__ unsigned short tile[32][66];  // pad 66: read-phase bank = k mod 32
  const int b = blockIdx.x, t = threadIdx.x;
  if (b < HIST_GS) {
    // degree histogram FIRST: co-resident with x2b, atomics hide under BW
    const int md = *mode;
    const int TH = HIST_GS * 256;
    for (int e = b * 256 + t; e < N_EDGES; e += TH) {
      int d = load_idx(ei, md, N_EDGES + e, N_NODES);
      atomicAdd(&deg[d], 1);
    }
  } else if (b < HIST_GS + X2B_GS) {
    // grid-stride over 4-col chunks; 4 independent loads in flight per thread.
    const int TH = X2B_GS * 256;
    for (int c = (b - HIST_GS) * 256 + t; c < X2B_TOT; c += 4 * TH) {
      int cc[4], rw[4], qq[4]; float4 v[4]; bool ld[4];
#pragma unroll
      for (int u = 0; u < 4; ++u) {
        cc[u] = c + u * TH;
        ld[u] = false; rw[u] = 0; qq[u] = 0;
        if (cc[u] < X2B_TOT) {
          rw[u] = cc[u] / 264;              // magic-mul
          qq[u] = cc[u] - rw[u] * 264;
          if (qq[u] < 257) {                // cols [0,1028): real data
            v[u] = *(const float4*)(x + (size_t)rw[u] * D_IN + 4 * qq[u]);
            ld[u] = true;
          }
        }
      }
#pragma unroll
      for (int u = 0; u < 4; ++u) {
        if (cc[u] < X2B_TOT) {
          ushort4 o = {0, 0, 0, 0};
          if (ld[u]) { o.x = f2bf(v[u].x); o.y = f2bf(v[u].y);
                       o.z = f2bf(v[u].z); o.w = f2bf(v[u].w); }
          *(ushort4*)(xb + (size_t)rw[u] * KPAD + 4 * qq[u]) = o;
        }
      }
    }
  } else {
    // LDS-tiled transpose: 32k x 64n tile, both global sides coalesced.
    const int w = b - HIST_GS - X2B_GS;
    const int k0 = (w >> 3) * 32, n0 = (w & 7) * 64;
#pragma unroll
    for (int j = 0; j < 8; ++j) {          // load: consecutive t -> consecutive n
      int k = 4 * j + (t >> 6), n = t & 63;
      unsigned short val = 0;
      if (k0 + k < D_IN) {
        int gn = n0 + n;
        val = f2bf(gn < D_OUT ? Wl[(size_t)(k0 + k) * D_OUT + gn]
                              : Wr[(size_t)(k0 + k) * D_OUT + (gn - D_OUT)]);
      }
      tile[k][n] = val;
    }
    __syncthreads();
#pragma unroll
    for (int j = 0; j < 8; ++j) {          // store: consecutive t -> consecutive k
      int n = 8 * j + (t >> 5), k = t & 31;
      Wt[(size_t)(n0 + n) * KPAD + k0 + k] = tile[k][n];
    }
  }
}

// ---------------- coalesced 2-kernel exclusive scan --------------------------
// scansum: per-block (256 elems) sums, fully coalesced.
__global__ __launch_bounds__(256) void k_scansum(const int* __restrict__ deg,
    int* __restrict__ bsum, int n) {
  __shared__ int wsum[4];
  const int b = (int)blockIdx.x, t = (int)threadIdx.x;
  const int lane = t & 63, wid = t >> 6;
  int i = b * 256 + t;
  int v = (i < n) ? deg[i] : 0;
#pragma unroll
  for (int off = 32; off; off >>= 1) v += __shfl_xor(v, off, 64);
  if (lane == 0) wsum[wid] = v;
  __syncthreads();
  if (t == 0) bsum[b] = wsum[0] + wsum[1] + wsum[2] + wsum[3];
}
// scanapply: every block redundantly scans the 196 block sums in LDS, then
// block-local exclusive scan of its 256 deg values; writes rowstart+cursor.
__global__ __launch_bounds__(256) void k_scanapply(const int* __restrict__ deg,
    const int* __restrict__ bsum, int* __restrict__ rowstart,
    int* __restrict__ cursor, int n) {
  __shared__ int bs[256];
  __shared__ int ws[4];
  const int b = (int)blockIdx.x, t = (int)threadIdx.x;
  const int lane = t & 63, wid = t >> 6;

  bs[t] = (t < NBLK) ? bsum[t] : 0;
  __syncthreads();
#pragma unroll
  for (int off = 1; off < 256; off <<= 1) {   // Hillis-Steele inclusive
    int v = bs[t] + ((t >= off) ? bs[t - off] : 0);
    __syncthreads();
    bs[t] = v;
    __syncthreads();
  }
  const int off_b = (b == 0) ? 0 : bs[b - 1];

  int i = b * 256 + t;
  int v = (i < n) ? deg[i] : 0;
  int x = v;                                  // wave inclusive scan
#pragma unroll
  for (int off = 1; off < 64; off <<= 1) {
    int y = __shfl_up(x, off, 64);
    if (lane >= off) x += y;
  }
  if (lane == 63) ws[wid] = x;
  __syncthreads();
  if (t < 4) {                                // exclusive scan of 4 wave sums
    int vv = ws[t], s = vv;
#pragma unroll
    for (int off = 1; off < 4; off <<= 1) {
      int y = __shfl_up(s, off, 4);
      if (t >= off) s += y;
    }
    ws[t] = s - vv;
  }
  __syncthreads();
  int excl = off_b + ws[wid] + (x - v);
  if (i < n) { rowstart[i] = excl; cursor[i] = excl; }
  if (b == 0 && t == 0) rowstart[n] = bs[NBLK - 1];
}

// ---------------- GEMM (R2-form, bf16 gl_lds) || scatter ---------------------
// blocks [0,GEMM_MN): 128x128 tile, BK=32, 16x16x32 mfma, 4 waves 64x64 each.
// blocks [GEMM_MN, GS_BLOCKS): CSR scatter (independent; needs scan done).
__global__ __launch_bounds__(256) void k_gemm(const unsigned short* __restrict__ xb,
    const unsigned short* __restrict__ Wt, unsigned short* __restrict__ xf, int M,
    const int* __restrict__ ei, const int* __restrict__ mode,
    int* __restrict__ cursor, int* __restrict__ ssrc) {
  const int bid = (int)blockIdx.x;
  if (bid >= GEMM_MN) {                    // ---- overlapped scatter ----
    const int md = *mode;
    const int TH = SCAT_B * 256;
    for (int e = (bid - GEMM_MN) * 256 + (int)threadIdx.x; e < N_EDGES; e += TH) {
      int s = load_idx(ei, md, e, N_NODES);
      int d = load_idx(ei, md, N_EDGES + e, N_NODES);
      int pos = atomicAdd(&cursor[d], 1);
      if (pos >= 0 && pos < N_EDGES) ssrc[pos] = s;
    }
    return;
  }
  __shared__ unsigned short smem[16896];  // As[0,4096) Bs[4096,8192); Cs overlays
  unsigned short* As = smem;
  unsigned short* Bs = smem + 4096;
  unsigned short* Cs = smem;
  const int tid = threadIdx.x;
  const int w = tid >> 6, lane = tid & 63;
  const int m0 = (bid % M_TILES) * 128, n0 = (bid / M_TILES) * 128;
  const int wm = (w >> 1) * 64, wn = (w & 1) * 64;

  f32x4 zero = {0.f, 0.f, 0.f, 0.f};
  f32x4 acc[4][4];
#pragma unroll
  for (int i = 0; i < 4; ++i)
#pragma unroll
    for (int j = 0; j < 4; ++j) acc[i][j] = zero;

  const int lrow = lane >> 2, lch = lane & 3;  // 16 rows x 4 x16B chunks / call

  for (int k0 = 0; k0 < KPAD; k0 += 32) {
    __syncthreads();
#pragma unroll
    for (int j = 0; j < 2; ++j) {
      int gm = m0 + w * 32 + j * 16 + lrow;
      if (gm >= M) gm = M - 1;
      const char* g = (const char*)xb + ((size_t)gm * KPAD + k0) * 2 + lch * 16;
      gl_lds16(g, &As[(w * 32 + j * 16) * 32]);
    }
#pragma unroll
    for (int j = 0; j < 2; ++j) {
      int gn = n0 + w * 32 + j * 16 + lrow;
      const char* g = (const char*)Wt + ((size_t)gn * KPAD + k0) * 2 + lch * 16;
      gl_lds16(g, &Bs[(w * 32 + j * 16) * 32]);
    }
    __syncthreads();

    bf16x8 af[4], bfr[4];
#pragma unroll
    for (int t = 0; t < 4; ++t)
      af[t] = *(const bf16x8*)&As[(wm + t * 16 + (lane & 15)) * 32 + (lane >> 4) * 8];
#pragma unroll
    for (int t = 0; t < 4; ++t)
      bfr[t] = *(const bf16x8*)&Bs[(wn + t * 16 + (lane & 15)) * 32 + (lane >> 4) * 8];
#pragma unroll
    for (int mt = 0; mt < 4; ++mt)
#pragma unroll
      for (int nt = 0; nt < 4; ++nt)
        acc[mt][nt] = __builtin_amdgcn_mfma_f32_16x16x32_bf16(af[mt], bfr[nt], acc[mt][nt], 0, 0, 0);
  }

  // C/D layout: col = lane&15, row = (lane>>4)*4 + r
  __syncthreads();  // all As/Bs reads done before Cs overlay
  {
    const int col = lane & 15, rq = (lane >> 4) * 4;
#pragma unroll
    for (int mt = 0; mt < 4; ++mt)
#pragma unroll
      for (int nt = 0; nt < 4; ++nt)
#pragma unroll
        for (int r = 0; r < 4; ++r)
          Cs[(wm + mt * 16 + rq + r) * 132 + wn + nt * 16 + col] = f2bf(acc[mt][nt][r]);
  }
  __syncthreads();
  {
    const int row = tid >> 1, half = tid & 1;  // 2 threads per row, 128B each
    int gm = m0 + row;
    if (gm < M) {
      unsigned short* dst = xf + (size_t)gm * NB + n0 + half * 64;
      const unsigned short* srcp = &Cs[row * 132 + half * 64];
#pragma unroll
      for (int j = 0; j < 8; ++j)
        *(uint4*)(dst + j * 8) = *(const uint4*)(srcp + j * 8);
    }
  }
}

// ---------------- fused gather + online softmax + aggregate ------------------
// Wave = 2 groups x 32 lanes; lane covers dims [8*gl, 8*gl+8); depth-2;
// defer-rescale (e<=m group-uniform path skips acc rescale).
static __device__ __forceinline__ void unpack8(uint4 u, float* v) {
  union { unsigned int i; float f; } c;
  c.i = u.x << 16;         v[0] = c.f;
  c.i = u.x & 0xffff0000u; v[1] = c.f;
  c.i = u.y << 16;         v[2] = c.f;
  c.i = u.y & 0xffff0000u; v[3] = c.f;
  c.i = u.z << 16;         v[4] = c.f;
  c.i = u.z & 0xffff0000u; v[5] = c.f;
  c.i = u.w << 16;         v[6] = c.f;
  c.i = u.w & 0xffff0000u; v[7] = c.f;
}
static __device__ __forceinline__ float dot8(const float* v, const float* xr, const float* a) {
  float e = 0.f;
#pragma unroll
  for (int d = 0; d < 8; ++d) {
    float t = v[d] + xr[d];
    t = fmaxf(t, 0.2f * t);        // LeakyReLU(0.2)
    e = fmaf(a[d], t, e);
  }
  return e;
}
static __device__ __forceinline__ float red32(float e) {
#pragma unroll
  for (int off = 1; off < 32; off <<= 1) e += __shfl_xor(e, off, 64);
  return e;
}

__global__ __launch_bounds__(256) void k_gat(const unsigned short* __restrict__ xf,
    const int* __restrict__ rowstart, const int* __restrict__ ssrc,
    const float* __restrict__ att, const float* __restrict__ bias,
    float* __restrict__ out, int n) {
  const int gw = (int)blockIdx.x * 4 + (int)(threadIdx.x >> 6);  // 1 wave/dst
  const int lane = (int)(threadIdx.x & 63);
  const int grp = lane >> 5, gl = lane & 31;
  if (gw >= n) return;

  float a[8];
  {
    float4 A0 = ((const float4*)att)[2 * gl];
    float4 A1 = ((const float4*)att)[2 * gl + 1];
    a[0] = A0.x; a[1] = A0.y; a[2] = A0.z; a[3] = A0.w;
    a[4] = A1.x; a[5] = A1.y; a[6] = A1.z; a[7] = A1.w;
  }
  float xr[8], vs[8];
  unpack8(*(const uint4*)(xf + (size_t)gw * NB + D_OUT + 8 * gl), xr);
  unpack8(*(const uint4*)(xf + (size_t)gw * NB + 8 * gl), vs);   // self row (xl)

  // self-loop into group 0; group 1 starts empty
  float m, l, acc[8];
  {
    float e = red32(dot8(vs, xr, a));
    if (grp == 0) {
      m = e; l = 1.f;
#pragma unroll
      for (int d = 0; d < 8; ++d) acc[d] = vs[d];
    } else {
      m = -1e30f; l = 0.f;
#pragma unroll
      for (int d = 0; d < 8; ++d) acc[d] = 0.f;
    }
  }

  const int end = rowstart[gw + 1];
  int i = rowstart[gw] + grp;                     // group g: edges beg+g, +2, ...
  bool have = i < end;
  uint4 vu;
  if (have) {
    unsigned s = (unsigned)ssrc[i];
    vu = *(const uint4*)(xf + ((size_t)s << 9) + 8 * gl);
  }
  while (have) {
    int i2 = i + 2;
    bool have2 = i2 < end;
    uint4 vu2;
    if (have2) {                                  // depth-2 pipeline: prefetch
      unsigned s2 = (unsigned)ssrc[i2];
      vu2 = *(const uint4*)(xf + ((size_t)s2 << 9) + 8 * gl);
    }
    float v[8];
    unpack8(vu, v);
    float e = red32(dot8(v, xr, a));
    if (e <= m) {                                 // common: max unchanged
      float p = __expf(e - m);
#pragma unroll
      for (int d = 0; d < 8; ++d) acc[d] = fmaf(p, v[d], acc[d]);
      l += p;
    } else {                                      // new max: p = 1
      float sc = __expf(m - e);
#pragma unroll
      for (int d = 0; d < 8; ++d) acc[d] = fmaf(acc[d], sc, v[d]);
      l = fmaf(l, sc, 1.f);
      m = e;
    }
    vu = vu2; i = i2; have = have2;
  }

  // flash-merge the two groups (lane L and L+32 hold the same dims)
  float mo = __shfl_xor(m, 32, 64);
  float mM = fmaxf(m, mo);
  float sA = __expf(m - mM);
  float lA = l * sA;
  float lS = lA + __shfl_xor(lA, 32, 64);
  float inv = 1.f / lS;
#pragma unroll
  for (int d = 0; d < 8; ++d) {
    float t = acc[d] * sA;
    acc[d] = t + __shfl_xor(t, 32, 64);
  }
  if (grp == 0) {
    float4 B0 = ((const float4*)bias)[2 * gl];
    float4 B1 = ((const float4*)bias)[2 * gl + 1];
    float4 o0, o1;
    o0.x = fmaf(acc[0], inv, B0.x); o0.y = fmaf(acc[1], inv, B0.y);
    o0.z = fmaf(acc[2], inv, B0.z); o0.w = fmaf(acc[3], inv, B0.w);
    o1.x = fmaf(acc[4], inv, B1.x); o1.y = fmaf(acc[5], inv, B1.y);
    o1.z = fmaf(acc[6], inv, B1.z); o1.w = fmaf(acc[7], inv, B1.w);
    ((float4*)out)[(size_t)gw * 64 + 2 * gl] = o0;
    ((float4*)out)[(size_t)gw * 64 + 2 * gl + 1] = o1;
  }
}

// ---------------- launch -----------------------------------------------------
extern "C" void kernel_launch(void* const* d_in, const int* in_sizes, int n_in,
                              void* d_out, int out_size, void* d_ws, size_t ws_size,
                              hipStream_t stream) {
  (void)in_sizes; (void)n_in; (void)out_size; (void)ws_size;
  const float* x   = (const float*)d_in[0];
  const int*   ei  = (const int*)d_in[1];
  const float* Wl  = (const float*)d_in[2];
  const float* Wr  = (const float*)d_in[3];
  const float* att = (const float*)d_in[4];
  const float* bia = (const float*)d_in[5];
  float* out = (float*)d_out;

  const int N = N_NODES;
  const int E = N_EDGES;

  char* ws = (char*)d_ws;
  size_t off = 0;
  unsigned short* xb = (unsigned short*)(ws + off); off += (size_t)N * KPAD * 2;  // 105.6 MB
  unsigned short* xf = (unsigned short*)(ws + off); off += (size_t)N * NB * 2;    //  51.2 MB
  unsigned short* Wt = (unsigned short*)(ws + off); off += (size_t)NB * KPAD * 2; //   1.1 MB
  off = (off + 255) & ~(size_t)255;
  int* deg      = (int*)(ws + off); off += (size_t)N * 4;
  int* mode     = (int*)(ws + off); off += 256;   // adjacent to deg: one memset
  int* bsum     = (int*)(ws + off); off += (size_t)NBLK * 4;
  off = (off + 255) & ~(size_t)255;
  int* rowstart = (int*)(ws + off); off += (size_t)(N + 1) * 4;
  off = (off + 255) & ~(size_t)255;
  int* cursor   = (int*)(ws + off); off += (size_t)N * 4;
  int* ssrc     = (int*)(ws + off); off += (size_t)E * 4;   // total ~165 MB

  hipMemsetAsync(deg, 0, (size_t)N * 4 + 256, stream);      // deg + mode
  k_mode<<<8, 256, 0, stream>>>((const unsigned int*)ei, mode);
  k_prep<<<PREP_BLOCKS, 256, 0, stream>>>(x, Wl, Wr, ei, mode, xb, Wt, deg);
  k_scansum<<<NBLK, 256, 0, stream>>>(deg, bsum, N);
  k_scanapply<<<NBLK, 256, 0, stream>>>(deg, bsum, rowstart, cursor, N);
  k_gemm<<<GS_BLOCKS, 256, 0, stream>>>(xb, Wt, xf, N, ei, mode, cursor, ssrc);
  k_gat<<<(N + 3) / 4, 256, 0, stream>>>(xf, rowstart, ssrc, att, bia, out, N);
}